// Round 1
// baseline (1951.525 us; speedup 1.0000x reference)
//
#include <hip/hip_runtime.h>
#include <cstdint>
#include <cstddef>

#define NB1      16384      // 2^14 first-level radix bins
#define L1SHIFT  18         // key >> 18 -> 14-bit bin
#define CAP      4096       // compaction buffer per task (power of 2 for bitonic)
#define K_TOP    1000
#define NCAND    5000
#define NIMG     8
#define NLVL     5
#define NTASK    40
#define NPOST    300
#define NEGF     (-1e9f)

struct Ptrs {
    const float* lg[5];
    const float* dl[5];
};

__device__ __forceinline__ unsigned key_of(float f) {
    unsigned u = __float_as_uint(f);
    return (u & 0x80000000u) ? ~u : (u | 0x80000000u);
}
__device__ __forceinline__ float key_to_float(unsigned k) {
    unsigned u = (k & 0x80000000u) ? (k ^ 0x80000000u) : ~k;
    return __uint_as_float(u);
}

// ---------------- zero scratch ----------------
__global__ void kZero(unsigned* p, size_t n) {
    size_t i = (size_t)blockIdx.x * blockDim.x + threadIdx.x;
    size_t st = (size_t)gridDim.x * blockDim.x;
    for (; i < n; i += st) p[i] = 0u;
}

// ---------------- pass 1: 14-bit histogram per (img,lvl) task ----------------
__global__ void kHist(const float* __restrict__ lg, int m, int lvl,
                      unsigned* __restrict__ hist) {
    int img = blockIdx.y;
    int j = blockIdx.x * blockDim.x + threadIdx.x;
    if (j < m) {
        unsigned key = key_of(lg[(size_t)img * m + j]);
        atomicAdd(&hist[(size_t)(img * NLVL + lvl) * NB1 + (key >> L1SHIFT)], 1u);
    }
}

// ---------------- pass 2: find 14-bit prefix of the K-th largest ----------------
__global__ __launch_bounds__(256) void kSelectBin(const unsigned* __restrict__ hist,
                                                  unsigned* __restrict__ tinfo,
                                                  unsigned* __restrict__ cnt) {
    int task = blockIdx.x;
    const unsigned* h = hist + (size_t)task * NB1;
    __shared__ unsigned sblk[256];
    __shared__ unsigned sbin[64];
    __shared__ int sh_tb;
    __shared__ unsigned sh_rem;
    int t = threadIdx.x;
    unsigned s = 0;
    for (int i = 0; i < 64; ++i) s += h[t * 64 + i];
    sblk[t] = s;
    __syncthreads();
    if (t == 0) {
        unsigned rem = K_TOP; int tb = 0;
        for (int b = 255; b >= 0; --b) {
            if (sblk[b] < rem) rem -= sblk[b];
            else { tb = b; break; }
        }
        sh_tb = tb; sh_rem = rem;
    }
    __syncthreads();
    if (t < 64) sbin[t] = h[sh_tb * 64 + t];
    __syncthreads();
    if (t == 0) {
        unsigned rem = sh_rem; int pfx = sh_tb * 64;
        for (int b = 63; b >= 0; --b) {
            if (sbin[b] < rem) rem -= sbin[b];
            else { pfx = sh_tb * 64 + b; break; }
        }
        tinfo[task * 2]     = (unsigned)pfx;
        tinfo[task * 2 + 1] = rem;
        cnt[task] = 0u;
    }
}

// ---------------- pass 3: compact all keys with bin >= prefix ----------------
__global__ void kCompact(const float* __restrict__ lg, int m, int lvl,
                         const unsigned* __restrict__ tinfo,
                         unsigned* __restrict__ cnt,
                         unsigned long long* __restrict__ compbuf) {
    int img = blockIdx.y;
    int task = img * NLVL + lvl;
    unsigned pfx = tinfo[task * 2];
    int j = blockIdx.x * blockDim.x + threadIdx.x;
    if (j < m) {
        unsigned key = key_of(lg[(size_t)img * m + j]);
        if ((key >> L1SHIFT) >= pfx) {
            unsigned pos = atomicAdd(&cnt[task], 1u);
            if (pos < CAP)
                compbuf[(size_t)task * CAP + pos] =
                    ((unsigned long long)key << 32) | (unsigned)(~j);
        }
    }
}

// ---------------- pass 4: sort candidates, decode boxes ----------------
__global__ __launch_bounds__(1024) void kSortSelect(
        Ptrs p,
        const unsigned* __restrict__ cnt,
        const unsigned long long* __restrict__ compbuf,
        float* __restrict__ cscore,
        float4* __restrict__ cbox,
        float4* __restrict__ cobox,
        float* __restrict__ carea) {
    int task = blockIdx.x;
    int img = task / NLVL, lvl = task % NLVL;
    __shared__ unsigned long long buf[CAP];
    int n = min((int)cnt[task], CAP);
    for (int i = threadIdx.x; i < CAP; i += 1024)
        buf[i] = (i < n) ? compbuf[(size_t)task * CAP + i] : 0ULL;
    __syncthreads();
    // bitonic sort, descending by composite ((key<<32)|~idx):
    // value desc, tie -> index asc (matches lax.top_k stability)
    for (int k = 2; k <= CAP; k <<= 1) {
        for (int j2 = k >> 1; j2 > 0; j2 >>= 1) {
            for (int i = threadIdx.x; i < CAP; i += 1024) {
                int pp = i ^ j2;
                if (pp > i) {
                    unsigned long long A = buf[i], B = buf[pp];
                    bool up = ((i & k) == 0);
                    if (up ? (A < B) : (A > B)) { buf[i] = B; buf[pp] = A; }
                }
            }
            __syncthreads();
        }
    }
    const int   MS[5]     = {516096, 129024, 32256, 8064, 2016};
    const int   GW[5]     = {512, 256, 128, 64, 32};
    const float STRIDEF[5]= {4.f, 8.f, 16.f, 32.f, 64.f};
    const int   SIZEI[5]  = {32, 64, 128, 256, 512};
    if (threadIdx.x < K_TOP) {
        int r = threadIdx.x;
        unsigned long long c = buf[r];
        int idx = (int)(~(unsigned)c);
        int m = MS[lvl];
        if ((unsigned)idx >= (unsigned)m) idx = 0;   // safety (never expected)
        const float* lg = p.lg[lvl];
        const float* dl = p.dl[lvl];
        float score = lg[(size_t)img * m + idx];
        int a   = idx % 3;
        int loc = idx / 3;
        int gw  = GW[lvl];
        int x = loc % gw, y = loc / gw;
        // cell anchors: double math then f32 cast, like numpy reference
        double ssz = (double)SIZEI[lvl];
        double arr = (a == 0) ? 0.5 : ((a == 1) ? 1.0 : 2.0);
        double wd = sqrt(ssz * ssz / arr);
        double hd = arr * wd;
        float sx = (float)x * STRIDEF[lvl];
        float sy = (float)y * STRIDEF[lvl];
        float a0 = sx + (float)(-wd * 0.5);
        float a1 = sy + (float)(-hd * 0.5);
        float a2 = sx + (float)( wd * 0.5);
        float a3 = sy + (float)( hd * 0.5);
        float aw = a2 - a0, ah = a3 - a1;
        float acx = a0 + 0.5f * aw, acy = a1 + 0.5f * ah;
        size_t db = ((size_t)img * m + idx) * 4;
        float dx = dl[db], dy = dl[db + 1], dwv = dl[db + 2], dhv = dl[db + 3];
        const float CL = 4.135166556742356f;   // log(1000/16)
        float pw = expf(fminf(dwv, CL)) * aw;
        float ph = expf(fminf(dhv, CL)) * ah;
        float pcx = dx * aw + acx;
        float pcy = dy * ah + acy;
        float x0 = pcx - 0.5f * pw, y0 = pcy - 0.5f * ph;
        float x1 = pcx + 0.5f * pw, y1 = pcy + 0.5f * ph;
        x0 = fminf(fmaxf(x0, 0.f), 2048.f);
        x1 = fminf(fmaxf(x1, 0.f), 2048.f);
        y0 = fminf(fmaxf(y0, 0.f), 1344.f);
        y1 = fminf(fmaxf(y1, 0.f), 1344.f);
        bool keep = ((x1 - x0) > 0.f) && ((y1 - y0) > 0.f);
        float sm = keep ? score : NEGF;
        float off = (float)lvl * 2049.0f;
        float b0 = x0 + off, b1 = y0 + off, b2 = x1 + off, b3 = y1 + off;
        float area = (b2 - b0) * (b3 - b1);
        int ci = img * NCAND + lvl * K_TOP + r;
        cscore[ci] = sm;
        cbox[ci]  = make_float4(x0, y0, x1, y1);
        cobox[ci] = make_float4(b0, b1, b2, b3);
        carea[ci] = area;
    }
}

// ---------------- pass 5: sequential NMS scan, 1 block per image ----------------
__global__ __launch_bounds__(1024) void kNMS(
        const float* __restrict__ cscore,
        const float4* __restrict__ cbox,
        const float4* __restrict__ cobox,
        const float* __restrict__ carea,
        float* __restrict__ out) {
    int img = blockIdx.x;
    int tid = threadIdx.x;
    __shared__ unsigned long long warr[16];
    __shared__ float bb[5];
    float s[5], b0[5], b1[5], b2[5], b3[5], ar[5];
#pragma unroll
    for (int k = 0; k < 5; ++k) {
        int j = tid + k * 1024;
        if (j < NCAND) {
            int ci = img * NCAND + j;
            s[k] = cscore[ci];
            float4 b = cobox[ci];
            b0[k] = b.x; b1[k] = b.y; b2[k] = b.z; b3[k] = b.w;
            ar[k] = carea[ci];
        } else {
            s[k] = -3.4e38f;
            b0[k] = b1[k] = b2[k] = b3[k] = 0.f; ar[k] = 0.f;
        }
    }
    for (int step = 0; step < NPOST; ++step) {
        unsigned long long comp = 0ULL;
#pragma unroll
        for (int k = 0; k < 5; ++k) {
            int j = tid + k * 1024;
            unsigned kk = key_of(s[k]);
            unsigned long long c = ((unsigned long long)kk << 32) | (unsigned)(~j);
            comp = (c > comp) ? c : comp;
        }
#pragma unroll
        for (int off2 = 32; off2 >= 1; off2 >>= 1) {
            unsigned long long o = __shfl_xor(comp, off2, 64);
            comp = (o > comp) ? o : comp;
        }
        if ((tid & 63) == 0) warr[tid >> 6] = comp;
        __syncthreads();
        unsigned long long best = warr[0];
#pragma unroll
        for (int w = 1; w < 16; ++w) {
            unsigned long long o = warr[w];
            best = (o > best) ? o : best;
        }
        int bidx = (int)(~(unsigned)best);
        float bscore = key_to_float((unsigned)(best >> 32));
        bool valid = bscore > -5.0e8f;
        // owner thread broadcasts chosen box + writes output row
#pragma unroll
        for (int k = 0; k < 5; ++k) {
            int j = tid + k * 1024;
            if (j == bidx) {
                bb[0] = b0[k]; bb[1] = b1[k]; bb[2] = b2[k]; bb[3] = b3[k]; bb[4] = ar[k];
                float* o = out + ((size_t)img * NPOST + step) * 5;
                if (valid) {
                    float4 gb = cbox[img * NCAND + j];
                    o[0] = gb.x; o[1] = gb.y; o[2] = gb.z; o[3] = gb.w; o[4] = bscore;
                } else {
                    o[0] = 0.f; o[1] = 0.f; o[2] = 0.f; o[3] = 0.f; o[4] = NEGF;
                }
            }
        }
        __syncthreads();
        float ib0 = bb[0], ib1 = bb[1], ib2 = bb[2], ib3 = bb[3], iar = bb[4];
#pragma unroll
        for (int k = 0; k < 5; ++k) {
            int j = tid + k * 1024;
            float ltx = fmaxf(b0[k], ib0), lty = fmaxf(b1[k], ib1);
            float rbx = fminf(b2[k], ib2), rby = fminf(b3[k], ib3);
            float wx = fmaxf(rbx - ltx, 0.f), wy = fmaxf(rby - lty, 0.f);
            float inter = wx * wy;
            float denom = ar[k] + iar;
            denom = denom - inter;
            denom = denom + 1e-9f;
            float iou = inter / denom;
            if (iou > 0.7f) s[k] = NEGF;
            if (j == bidx) s[k] = NEGF;
        }
    }
}

extern "C" void kernel_launch(void* const* d_in, const int* in_sizes, int n_in,
                              void* d_out, int out_size, void* d_ws, size_t ws_size,
                              hipStream_t stream) {
    const int MS[5] = {516096, 129024, 32256, 8064, 2016};
    Ptrs P;
    for (int l = 0; l < 5; ++l) {
        P.lg[l] = (const float*)d_in[2 * l];
        P.dl[l] = (const float*)d_in[2 * l + 1];
    }
    char* w = (char*)d_ws;
    size_t off = 0;
    auto alloc = [&](size_t bytes) -> void* {
        void* pp = (void*)(w + off);
        off = (off + bytes + 255) & ~(size_t)255;
        return pp;
    };
    unsigned* hist            = (unsigned*)alloc((size_t)NTASK * NB1 * 4);
    unsigned* tinfo           = (unsigned*)alloc(NTASK * 2 * 4);
    unsigned* cnt             = (unsigned*)alloc(NTASK * 4);
    unsigned long long* compb = (unsigned long long*)alloc((size_t)NTASK * CAP * 8);
    float*  cscore            = (float*)alloc((size_t)NTASK * K_TOP * 4);
    float4* cbox              = (float4*)alloc((size_t)NTASK * K_TOP * 16);
    float4* cobox             = (float4*)alloc((size_t)NTASK * K_TOP * 16);
    float*  carea             = (float*)alloc((size_t)NTASK * K_TOP * 4);
    (void)ws_size; (void)in_sizes; (void)n_in; (void)out_size;

    size_t nhz = (size_t)NTASK * NB1;
    kZero<<<2048, 256, 0, stream>>>(hist, nhz);
    for (int l = 0; l < 5; ++l) {
        dim3 g((MS[l] + 255) / 256, NIMG);
        kHist<<<g, 256, 0, stream>>>(P.lg[l], MS[l], l, hist);
    }
    kSelectBin<<<NTASK, 256, 0, stream>>>(hist, tinfo, cnt);
    for (int l = 0; l < 5; ++l) {
        dim3 g((MS[l] + 255) / 256, NIMG);
        kCompact<<<g, 256, 0, stream>>>(P.lg[l], MS[l], l, tinfo, cnt, compb);
    }
    kSortSelect<<<NTASK, 1024, 0, stream>>>(P, cnt, compb, cscore, cbox, cobox, carea);
    kNMS<<<NIMG, 1024, 0, stream>>>(cscore, cbox, cobox, carea, (float*)d_out);
}

// Round 3
// 1445.275 us; speedup vs baseline: 1.3503x; 1.3503x over previous
//
#include <hip/hip_runtime.h>
#include <cstdint>
#include <cstddef>

#define NB1      16384      // 2^14 first-level radix bins
#define L1SHIFT  18         // key >> 18 -> 14-bit bin
#define CAP      4096       // compaction buffer per task (power of 2 for bitonic)
#define K_TOP    1000
#define NCAND    5000
#define NIMG     8
#define NLVL     5
#define NTASK    40
#define NPOST    300
#define NEGF     (-1e9f)
#define NWORDS   79         // ceil(5000/64)
#define RSTRIDE  80         // u64 row stride for suppression matrix

typedef unsigned long long u64;

struct Ptrs {
    const float* lg[5];
    const float* dl[5];
};

__device__ __forceinline__ unsigned key_of(float f) {
    unsigned u = __float_as_uint(f);
    return (u & 0x80000000u) ? ~u : (u | 0x80000000u);
}
__device__ __forceinline__ float key_to_float(unsigned k) {
    unsigned u = (k & 0x80000000u) ? (k ^ 0x80000000u) : ~k;
    return __uint_as_float(u);
}

// ---------------- zero scratch ----------------
__global__ void kZero(unsigned* p, size_t n) {
    size_t i = (size_t)blockIdx.x * blockDim.x + threadIdx.x;
    size_t st = (size_t)gridDim.x * blockDim.x;
    for (; i < n; i += st) p[i] = 0u;
}

// ---------------- pass 1: 14-bit histogram per (img,lvl) task ----------------
__global__ void kHist(const float* __restrict__ lg, int m, int lvl,
                      unsigned* __restrict__ hist) {
    int img = blockIdx.y;
    int j = blockIdx.x * blockDim.x + threadIdx.x;
    if (j < m) {
        unsigned key = key_of(lg[(size_t)img * m + j]);
        atomicAdd(&hist[(size_t)(img * NLVL + lvl) * NB1 + (key >> L1SHIFT)], 1u);
    }
}

// ---------------- pass 2: find 14-bit prefix of the K-th largest ----------------
__global__ __launch_bounds__(256) void kSelectBin(const unsigned* __restrict__ hist,
                                                  unsigned* __restrict__ tinfo,
                                                  unsigned* __restrict__ cnt) {
    int task = blockIdx.x;
    const unsigned* h = hist + (size_t)task * NB1;
    __shared__ unsigned sblk[256];
    __shared__ unsigned sbin[64];
    __shared__ int sh_tb;
    __shared__ unsigned sh_rem;
    int t = threadIdx.x;
    unsigned s = 0;
    for (int i = 0; i < 64; ++i) s += h[t * 64 + i];
    sblk[t] = s;
    __syncthreads();
    if (t == 0) {
        unsigned rem = K_TOP; int tb = 0;
        for (int b = 255; b >= 0; --b) {
            if (sblk[b] < rem) rem -= sblk[b];
            else { tb = b; break; }
        }
        sh_tb = tb; sh_rem = rem;
    }
    __syncthreads();
    if (t < 64) sbin[t] = h[sh_tb * 64 + t];
    __syncthreads();
    if (t == 0) {
        unsigned rem = sh_rem; int pfx = sh_tb * 64;
        for (int b = 63; b >= 0; --b) {
            if (sbin[b] < rem) rem -= sbin[b];
            else { pfx = sh_tb * 64 + b; break; }
        }
        tinfo[task * 2]     = (unsigned)pfx;
        tinfo[task * 2 + 1] = rem;
        cnt[task] = 0u;
    }
}

// ---------------- pass 3: compact all keys with bin >= prefix ----------------
__global__ void kCompact(const float* __restrict__ lg, int m, int lvl,
                         const unsigned* __restrict__ tinfo,
                         unsigned* __restrict__ cnt,
                         u64* __restrict__ compbuf) {
    int img = blockIdx.y;
    int task = img * NLVL + lvl;
    unsigned pfx = tinfo[task * 2];
    int j = blockIdx.x * blockDim.x + threadIdx.x;
    if (j < m) {
        unsigned key = key_of(lg[(size_t)img * m + j]);
        if ((key >> L1SHIFT) >= pfx) {
            unsigned pos = atomicAdd(&cnt[task], 1u);
            if (pos < CAP)
                compbuf[(size_t)task * CAP + pos] =
                    ((u64)key << 32) | (unsigned)(~j);
        }
    }
}

// ---------------- pass 4: sort candidates, decode boxes, resort by masked score ----
// Output per-level lists sorted by (masked score desc, orig concat index asc);
// cog[] carries the original within-level rank (= reference top-k position).
__global__ __launch_bounds__(1024) void kSortSelect(
        Ptrs p,
        const unsigned* __restrict__ cnt,
        const u64* __restrict__ compbuf,
        float* __restrict__ cscore,
        float4* __restrict__ cbox,
        float4* __restrict__ cobox,
        float* __restrict__ carea,
        unsigned* __restrict__ cog) {
    int task = blockIdx.x;
    int img = task / NLVL, lvl = task % NLVL;
    __shared__ u64 sortbuf[CAP + 1024];   // 40 KB; phase-2 reused as float farr[10240]
    __shared__ u64 buf2[1024];
    u64* buf = sortbuf;
    int n = min((int)cnt[task], CAP);
    for (int i = threadIdx.x; i < CAP; i += 1024)
        buf[i] = (i < n) ? compbuf[(size_t)task * CAP + i] : 0ULL;
    __syncthreads();
    // bitonic sort, descending by composite ((key<<32)|~idx):
    // value desc, tie -> index asc (matches lax.top_k stability)
    for (int k = 2; k <= CAP; k <<= 1) {
        for (int j2 = k >> 1; j2 > 0; j2 >>= 1) {
            for (int i = threadIdx.x; i < CAP; i += 1024) {
                int pp = i ^ j2;
                if (pp > i) {
                    u64 A = buf[i], B = buf[pp];
                    bool up = ((i & k) == 0);
                    if (up ? (A < B) : (A > B)) { buf[i] = B; buf[pp] = A; }
                }
            }
            __syncthreads();
        }
    }
    const int   MS[5]     = {516096, 129024, 32256, 8064, 2016};
    const int   GW[5]     = {512, 256, 128, 64, 32};
    const float STRIDEF[5]= {4.f, 8.f, 16.f, 32.f, 64.f};
    const int   SIZEI[5]  = {32, 64, 128, 256, 512};
    int r = threadIdx.x;
    float sm = 0.f, x0 = 0.f, y0 = 0.f, x1 = 0.f, y1 = 0.f;
    float b0 = 0.f, b1 = 0.f, b2 = 0.f, b3 = 0.f, area = 0.f;
    if (r < K_TOP) {
        u64 c = buf[r];
        int idx = (int)(~(unsigned)c);
        int m = MS[lvl];
        if ((unsigned)idx >= (unsigned)m) idx = 0;   // safety (never expected)
        const float* lg = p.lg[lvl];
        const float* dl = p.dl[lvl];
        float score = lg[(size_t)img * m + idx];
        int a   = idx % 3;
        int loc = idx / 3;
        int gw  = GW[lvl];
        int x = loc % gw, y = loc / gw;
        // cell anchors: double math then f32 cast, like numpy reference
        double ssz = (double)SIZEI[lvl];
        double arr = (a == 0) ? 0.5 : ((a == 1) ? 1.0 : 2.0);
        double wd = sqrt(ssz * ssz / arr);
        double hd = arr * wd;
        float sx = (float)x * STRIDEF[lvl];
        float sy = (float)y * STRIDEF[lvl];
        float a0 = sx + (float)(-wd * 0.5);
        float a1 = sy + (float)(-hd * 0.5);
        float a2 = sx + (float)( wd * 0.5);
        float a3 = sy + (float)( hd * 0.5);
        float aw = a2 - a0, ah = a3 - a1;
        float acx = a0 + 0.5f * aw, acy = a1 + 0.5f * ah;
        size_t db = ((size_t)img * m + idx) * 4;
        float dx = dl[db], dy = dl[db + 1], dwv = dl[db + 2], dhv = dl[db + 3];
        const float CL = 4.135166556742356f;   // log(1000/16)
        float pw = expf(fminf(dwv, CL)) * aw;
        float ph = expf(fminf(dhv, CL)) * ah;
        float pcx = dx * aw + acx;
        float pcy = dy * ah + acy;
        x0 = pcx - 0.5f * pw; y0 = pcy - 0.5f * ph;
        x1 = pcx + 0.5f * pw; y1 = pcy + 0.5f * ph;
        x0 = fminf(fmaxf(x0, 0.f), 2048.f);
        x1 = fminf(fmaxf(x1, 0.f), 2048.f);
        y0 = fminf(fmaxf(y0, 0.f), 1344.f);
        y1 = fminf(fmaxf(y1, 0.f), 1344.f);
        bool keep = ((x1 - x0) > 0.f) && ((y1 - y0) > 0.f);
        sm = keep ? score : NEGF;
        float off = (float)lvl * 2049.0f;
        b0 = x0 + off; b1 = y0 + off; b2 = x1 + off; b3 = y1 + off;
        area = (b2 - b0) * (b3 - b1);
    }
    __syncthreads();                 // all buf reads done before reuse as farr
    float* farr = (float*)sortbuf;   // [0,1000) score  [1000,2000) area
                                     // [2000,6000) clip box  [6000,10000) offset box
    if (r < K_TOP) {
        farr[r] = sm;
        farr[1000 + r] = area;
        farr[2000 + 4 * r]     = x0;
        farr[2000 + 4 * r + 1] = y0;
        farr[2000 + 4 * r + 2] = x1;
        farr[2000 + 4 * r + 3] = y1;
        farr[6000 + 4 * r]     = b0;
        farr[6000 + 4 * r + 1] = b1;
        farr[6000 + 4 * r + 2] = b2;
        farr[6000 + 4 * r + 3] = b3;
    }
    // composite on MASKED score, tie-break by original concat index (asc)
    buf2[r] = (r < K_TOP)
        ? (((u64)key_of(sm) << 32) | (unsigned)(~(unsigned)(lvl * K_TOP + r)))
        : 0ULL;
    __syncthreads();
    for (int k = 2; k <= 1024; k <<= 1) {
        for (int j2 = k >> 1; j2 > 0; j2 >>= 1) {
            int i = r, pp = i ^ j2;
            if (pp > i) {
                u64 A = buf2[i], B = buf2[pp];
                bool up = ((i & k) == 0);
                if (up ? (A < B) : (A > B)) { buf2[i] = B; buf2[pp] = A; }
            }
            __syncthreads();
        }
    }
    if (r < K_TOP) {
        u64 c2 = buf2[r];
        unsigned g2 = ~(unsigned)c2;
        int rsrc = (int)g2 - lvl * K_TOP;    // original within-level rank
        int ci = img * NCAND + lvl * K_TOP + r;
        cscore[ci] = farr[rsrc];
        carea[ci]  = farr[1000 + rsrc];
        cbox[ci]  = make_float4(farr[2000 + 4 * rsrc],     farr[2000 + 4 * rsrc + 1],
                                farr[2000 + 4 * rsrc + 2], farr[2000 + 4 * rsrc + 3]);
        cobox[ci] = make_float4(farr[6000 + 4 * rsrc],     farr[6000 + 4 * rsrc + 1],
                                farr[6000 + 4 * rsrc + 2], farr[6000 + 4 * rsrc + 3]);
        cog[ci] = (unsigned)rsrc;
    }
}

// ---------------- pass 5a: merge 5 sorted lists into global sorted order ----------------
// Per-level lists are sorted desc by (masked key, orig concat index asc), so
// composite (key<<32)|~orig_g is strictly decreasing within each level.
// rank = pos-in-own-level + sum over other levels of count{composite > mine}.
__global__ __launch_bounds__(1024) void kMerge(
        const float* __restrict__ cscore,
        const float4* __restrict__ cbox,
        const float4* __restrict__ cobox,
        const float* __restrict__ carea,
        const unsigned* __restrict__ cog,
        float* __restrict__ ssc,
        float4* __restrict__ sob,
        float* __restrict__ sar,
        float4* __restrict__ sclip) {
    int img = blockIdx.x;
    __shared__ u64 comp[NCAND];
    for (int g = threadIdx.x; g < NCAND; g += 1024) {
        int lv = g / K_TOP;
        unsigned og = (unsigned)(lv * K_TOP) + cog[img * NCAND + g];
        comp[g] = ((u64)key_of(cscore[img * NCAND + g]) << 32) | (unsigned)(~og);
    }
    __syncthreads();
    for (int g = threadIdx.x; g < NCAND; g += 1024) {
        u64 c = comp[g];
        int lv = g / K_TOP;
        int pos = g - lv * K_TOP;    // elements > c within own (desc-sorted) level
        for (int lv2 = 0; lv2 < NLVL; ++lv2) {
            if (lv2 == lv) continue;
            int base = lv2 * K_TOP;
            int lo = 0, hi = K_TOP;
            while (lo < hi) {
                int mid = (lo + hi) >> 1;
                if (comp[base + mid] > c) lo = mid + 1; else hi = mid;
            }
            pos += lo;               // count of elements > c (composites unique)
        }
        int src = img * NCAND + g;
        int dst = img * NCAND + pos;
        ssc[dst]   = cscore[src];
        sob[dst]   = cobox[src];
        sar[dst]   = carea[src];
        sclip[dst] = cbox[src];
    }
}

// ---------------- pass 5b: bit-packed suppression matrix ----------------
// row i (sorted order), word w: bit b = IoU(i, w*64+b) > 0.7. Only words w >= i>>6 stored.
__global__ __launch_bounds__(256) void kIou(
        const float4* __restrict__ sob,
        const float* __restrict__ sar,
        u64* __restrict__ mat) {
    int img  = blockIdx.y;
    int wid  = threadIdx.x >> 6;
    int lane = threadIdx.x & 63;
    int i = blockIdx.x * 4 + wid;
    if (i >= NCAND) return;
    float4 bi = sob[img * NCAND + i];
    float ari = sar[img * NCAND + i];
    int wstart = i >> 6;
    for (int w = wstart; w < NWORDS; ++w) {
        int j = w * 64 + lane;
        bool pred = false;
        if (j < NCAND) {
            float4 bj = sob[img * NCAND + j];
            float arj = sar[img * NCAND + j];
            float ltx = fmaxf(bj.x, bi.x), lty = fmaxf(bj.y, bi.y);
            float rbx = fminf(bj.z, bi.z), rby = fminf(bj.w, bi.w);
            float wx = fmaxf(rbx - ltx, 0.f), wy = fmaxf(rby - lty, 0.f);
            float inter = wx * wy;
            float denom = (arj + ari) - inter + 1e-9f;
            float iou = inter / denom;
            pred = iou > 0.7f;
        }
        u64 bits = __ballot(pred);
        if (lane == 0) mat[((size_t)(img * NCAND + i)) * RSTRIDE + w] = bits;
    }
}

// ---------------- pass 5c: word-tiled sequential scan (1 wave per image) ----------------
__global__ __launch_bounds__(64) void kScan(
        const float* __restrict__ ssc,
        const float4* __restrict__ sclip,
        const u64* __restrict__ mat,
        float* __restrict__ out) {
    int img  = blockIdx.x;
    int lane = threadIdx.x;
    __shared__ u64 maskS[NWORDS + 1];
    __shared__ u64 diagS[NWORDS * 64];
    __shared__ float sscS[NCAND];
    for (int w = lane; w < NWORDS + 1; w += 64) maskS[w] = 0ULL;
    // preload diagonal 64x64 blocks: diag[w][b] = mat[w*64+b][w]
    for (int it = 0; it < NWORDS; ++it) {
        int i = it * 64 + lane;
        diagS[it * 64 + lane] =
            (i < NCAND) ? mat[((size_t)(img * NCAND + i)) * RSTRIDE + it] : 0ULL;
    }
    for (int idx = lane; idx < NCAND; idx += 64)
        sscS[idx] = ssc[img * NCAND + idx];
    __syncthreads();

    int emitted = 0;
    bool done = false;
    for (int w = 0; w < NWORDS && !done; ++w) {
        u64 cur = ~maskS[w];
        if (w == NWORDS - 1) cur &= (1ULL << (NCAND - (NWORDS - 1) * 64)) - 1ULL;
        while (cur) {
            int b = __builtin_ctzll(cur);
            int i = w * 64 + b;
            float sc = sscS[i];
            if (sc <= -5.0e8f) { done = true; break; }   // all later are invalid too
            if (lane == 0) {
                float4 cb = sclip[img * NCAND + i];
                float* o = out + ((size_t)img * NPOST + emitted) * 5;
                o[0] = cb.x; o[1] = cb.y; o[2] = cb.z; o[3] = cb.w; o[4] = sc;
            }
            ++emitted;
            if (emitted == NPOST) { done = true; break; }
            u64 rw = diagS[w * 64 + b];
            cur &= ~rw;
            cur &= ~(1ULL << b);
            const u64* row = mat + ((size_t)(img * NCAND + i)) * RSTRIDE;
            int w2 = w + 1 + lane;
            if (w2 < NWORDS) maskS[w2] |= row[w2];
            int w3 = w + 65 + lane;
            if (w3 < NWORDS) maskS[w3] |= row[w3];
        }
        __syncthreads();   // make lane ORs visible before reading next mask word
    }
    for (int rr = emitted + lane; rr < NPOST; rr += 64) {
        float* o = out + ((size_t)img * NPOST + rr) * 5;
        o[0] = 0.f; o[1] = 0.f; o[2] = 0.f; o[3] = 0.f; o[4] = NEGF;
    }
}

// ---------------- fallback: round-1 sequential NMS (used only if ws too small) ----------------
__global__ __launch_bounds__(1024) void kNMS(
        const float* __restrict__ cscore,
        const float4* __restrict__ cbox,
        const float4* __restrict__ cobox,
        const float* __restrict__ carea,
        float* __restrict__ out) {
    int img = blockIdx.x;
    int tid = threadIdx.x;
    __shared__ u64 warr[16];
    __shared__ float bb[5];
    float s[5], b0[5], b1[5], b2[5], b3[5], ar[5];
#pragma unroll
    for (int k = 0; k < 5; ++k) {
        int j = tid + k * 1024;
        if (j < NCAND) {
            int ci = img * NCAND + j;
            s[k] = cscore[ci];
            float4 b = cobox[ci];
            b0[k] = b.x; b1[k] = b.y; b2[k] = b.z; b3[k] = b.w;
            ar[k] = carea[ci];
        } else {
            s[k] = -3.4e38f;
            b0[k] = b1[k] = b2[k] = b3[k] = 0.f; ar[k] = 0.f;
        }
    }
    for (int step = 0; step < NPOST; ++step) {
        u64 comp = 0ULL;
#pragma unroll
        for (int k = 0; k < 5; ++k) {
            int j = tid + k * 1024;
            unsigned kk = key_of(s[k]);
            u64 c = ((u64)kk << 32) | (unsigned)(~j);
            comp = (c > comp) ? c : comp;
        }
#pragma unroll
        for (int off2 = 32; off2 >= 1; off2 >>= 1) {
            u64 o = __shfl_xor(comp, off2, 64);
            comp = (o > comp) ? o : comp;
        }
        if ((tid & 63) == 0) warr[tid >> 6] = comp;
        __syncthreads();
        u64 best = warr[0];
#pragma unroll
        for (int w = 1; w < 16; ++w) {
            u64 o = warr[w];
            best = (o > best) ? o : best;
        }
        int bidx = (int)(~(unsigned)best);
        float bscore = key_to_float((unsigned)(best >> 32));
        bool valid = bscore > -5.0e8f;
#pragma unroll
        for (int k = 0; k < 5; ++k) {
            int j = tid + k * 1024;
            if (j == bidx) {
                bb[0] = b0[k]; bb[1] = b1[k]; bb[2] = b2[k]; bb[3] = b3[k]; bb[4] = ar[k];
                float* o = out + ((size_t)img * NPOST + step) * 5;
                if (valid) {
                    float4 gb = cbox[img * NCAND + j];
                    o[0] = gb.x; o[1] = gb.y; o[2] = gb.z; o[3] = gb.w; o[4] = bscore;
                } else {
                    o[0] = 0.f; o[1] = 0.f; o[2] = 0.f; o[3] = 0.f; o[4] = NEGF;
                }
            }
        }
        __syncthreads();
        float ib0 = bb[0], ib1 = bb[1], ib2 = bb[2], ib3 = bb[3], iar = bb[4];
#pragma unroll
        for (int k = 0; k < 5; ++k) {
            int j = tid + k * 1024;
            float ltx = fmaxf(b0[k], ib0), lty = fmaxf(b1[k], ib1);
            float rbx = fminf(b2[k], ib2), rby = fminf(b3[k], ib3);
            float wx = fmaxf(rbx - ltx, 0.f), wy = fmaxf(rby - lty, 0.f);
            float inter = wx * wy;
            float denom = ar[k] + iar;
            denom = denom - inter;
            denom = denom + 1e-9f;
            float iou = inter / denom;
            if (iou > 0.7f) s[k] = NEGF;
            if (j == bidx) s[k] = NEGF;
        }
    }
}

extern "C" void kernel_launch(void* const* d_in, const int* in_sizes, int n_in,
                              void* d_out, int out_size, void* d_ws, size_t ws_size,
                              hipStream_t stream) {
    const int MS[5] = {516096, 129024, 32256, 8064, 2016};
    Ptrs P;
    for (int l = 0; l < 5; ++l) {
        P.lg[l] = (const float*)d_in[2 * l];
        P.dl[l] = (const float*)d_in[2 * l + 1];
    }
    char* w = (char*)d_ws;
    size_t off = 0;
    auto alloc = [&](size_t bytes) -> void* {
        void* pp = (void*)(w + off);
        off = (off + bytes + 255) & ~(size_t)255;
        return pp;
    };
    unsigned* hist  = (unsigned*)alloc((size_t)NTASK * NB1 * 4);
    unsigned* tinfo = (unsigned*)alloc(NTASK * 2 * 4);
    unsigned* cnt   = (unsigned*)alloc(NTASK * 4);
    u64* compb      = (u64*)alloc((size_t)NTASK * CAP * 8);
    float*  cscore  = (float*)alloc((size_t)NTASK * K_TOP * 4);
    float4* cbox    = (float4*)alloc((size_t)NTASK * K_TOP * 16);
    float4* cobox   = (float4*)alloc((size_t)NTASK * K_TOP * 16);
    float*  carea   = (float*)alloc((size_t)NTASK * K_TOP * 4);
    unsigned* cog   = (unsigned*)alloc((size_t)NTASK * K_TOP * 4);
    // NMS scratch
    float*  ssc     = (float*)alloc((size_t)NIMG * NCAND * 4);
    float4* sob     = (float4*)alloc((size_t)NIMG * NCAND * 16);
    float*  sar     = (float*)alloc((size_t)NIMG * NCAND * 4);
    float4* sclip   = (float4*)alloc((size_t)NIMG * NCAND * 16);
    u64*    mat     = (u64*)alloc((size_t)NIMG * NCAND * RSTRIDE * 8);
    size_t need = off;
    (void)in_sizes; (void)n_in; (void)out_size;

    size_t nhz = (size_t)NTASK * NB1;
    kZero<<<2048, 256, 0, stream>>>(hist, nhz);
    for (int l = 0; l < 5; ++l) {
        dim3 g((MS[l] + 255) / 256, NIMG);
        kHist<<<g, 256, 0, stream>>>(P.lg[l], MS[l], l, hist);
    }
    kSelectBin<<<NTASK, 256, 0, stream>>>(hist, tinfo, cnt);
    for (int l = 0; l < 5; ++l) {
        dim3 g((MS[l] + 255) / 256, NIMG);
        kCompact<<<g, 256, 0, stream>>>(P.lg[l], MS[l], l, tinfo, cnt, compb);
    }
    kSortSelect<<<NTASK, 1024, 0, stream>>>(P, cnt, compb, cscore, cbox, cobox, carea, cog);

    if (ws_size >= need) {
        kMerge<<<NIMG, 1024, 0, stream>>>(cscore, cbox, cobox, carea, cog,
                                          ssc, sob, sar, sclip);
        dim3 gi((NCAND + 3) / 4, NIMG);
        kIou<<<gi, 256, 0, stream>>>(sob, sar, mat);
        kScan<<<NIMG, 64, 0, stream>>>(ssc, sclip, mat, (float*)d_out);
    } else {
        kNMS<<<NIMG, 1024, 0, stream>>>(cscore, cbox, cobox, carea, (float*)d_out);
    }
}

// Round 4
// 629.552 us; speedup vs baseline: 3.0999x; 2.2957x over previous
//
#include <hip/hip_runtime.h>
#include <cstdint>
#include <cstddef>

#define NB1      16384      // 2^14 first-level radix bins
#define L1SHIFT  18         // key >> 18 -> 14-bit bin
#define CAP      4096       // compaction buffer per task (power of 2 for bitonic)
#define K_TOP    1000
#define NCAND    5000
#define NIMG     8
#define NLVL     5
#define NTASK    40
#define NPOST    300
#define NEGF     (-1e9f)
#define NWORDS   79         // ceil(5000/64)
#define RSTRIDE  80         // u64 row stride for suppression matrix

typedef unsigned long long u64;

struct Ptrs {
    const float* lg[5];
    const float* dl[5];
};

__device__ __forceinline__ unsigned key_of(float f) {
    unsigned u = __float_as_uint(f);
    return (u & 0x80000000u) ? ~u : (u | 0x80000000u);
}
__device__ __forceinline__ float key_to_float(unsigned k) {
    unsigned u = (k & 0x80000000u) ? (k ^ 0x80000000u) : ~k;
    return __uint_as_float(u);
}

// ---------------- zero scratch ----------------
__global__ void kZero(unsigned* p, size_t n) {
    size_t i = (size_t)blockIdx.x * blockDim.x + threadIdx.x;
    size_t st = (size_t)gridDim.x * blockDim.x;
    for (; i < n; i += st) p[i] = 0u;
}

// ---------------- pass 1: LDS-privatized 14-bit histogram per (img,lvl) ----------------
// Each block: private LDS hist (64 KB), float4 loads, DS atomics, then flush
// only non-zero bins to the global per-task histogram.
__global__ __launch_bounds__(1024) void kHist(const float* __restrict__ lg,
                                              int m, int lvl,
                                              unsigned* __restrict__ hist) {
    int img  = blockIdx.y;
    int task = img * NLVL + lvl;
    __shared__ unsigned h[NB1];
    for (int i = threadIdx.x; i < NB1; i += 1024) h[i] = 0u;
    __syncthreads();
    int m4 = m >> 2;                       // all level sizes divisible by 4
    int chunk4 = (m4 + gridDim.x - 1) / (int)gridDim.x;
    int start4 = blockIdx.x * chunk4;
    int end4   = min(start4 + chunk4, m4);
    const float4* src = (const float4*)(lg + (size_t)img * m);
    for (int i = start4 + threadIdx.x; i < end4; i += 1024) {
        float4 v = src[i];
        atomicAdd(&h[key_of(v.x) >> L1SHIFT], 1u);
        atomicAdd(&h[key_of(v.y) >> L1SHIFT], 1u);
        atomicAdd(&h[key_of(v.z) >> L1SHIFT], 1u);
        atomicAdd(&h[key_of(v.w) >> L1SHIFT], 1u);
    }
    __syncthreads();
    unsigned* gh = hist + (size_t)task * NB1;
    for (int i = threadIdx.x; i < NB1; i += 1024) {
        unsigned c = h[i];
        if (c) atomicAdd(&gh[i], c);
    }
}

// ---------------- pass 2: find 14-bit prefix of the K-th largest ----------------
__global__ __launch_bounds__(256) void kSelectBin(const unsigned* __restrict__ hist,
                                                  unsigned* __restrict__ tinfo,
                                                  unsigned* __restrict__ cnt) {
    int task = blockIdx.x;
    const unsigned* h = hist + (size_t)task * NB1;
    __shared__ unsigned sblk[256];
    __shared__ unsigned sbin[64];
    __shared__ int sh_tb;
    __shared__ unsigned sh_rem;
    int t = threadIdx.x;
    unsigned s = 0;
    for (int i = 0; i < 64; ++i) s += h[t * 64 + i];
    sblk[t] = s;
    __syncthreads();
    if (t == 0) {
        unsigned rem = K_TOP; int tb = 0;
        for (int b = 255; b >= 0; --b) {
            if (sblk[b] < rem) rem -= sblk[b];
            else { tb = b; break; }
        }
        sh_tb = tb; sh_rem = rem;
    }
    __syncthreads();
    if (t < 64) sbin[t] = h[sh_tb * 64 + t];
    __syncthreads();
    if (t == 0) {
        unsigned rem = sh_rem; int pfx = sh_tb * 64;
        for (int b = 63; b >= 0; --b) {
            if (sbin[b] < rem) rem -= sbin[b];
            else { pfx = sh_tb * 64 + b; break; }
        }
        tinfo[task * 2]     = (unsigned)pfx;
        tinfo[task * 2 + 1] = rem;
        cnt[task] = 0u;
    }
}

// ---------------- pass 3: compact all keys with bin >= prefix ----------------
__global__ void kCompact(const float* __restrict__ lg, int m, int lvl,
                         const unsigned* __restrict__ tinfo,
                         unsigned* __restrict__ cnt,
                         u64* __restrict__ compbuf) {
    int img = blockIdx.y;
    int task = img * NLVL + lvl;
    unsigned pfx = tinfo[task * 2];
    int j = blockIdx.x * blockDim.x + threadIdx.x;
    if (j < m) {
        unsigned key = key_of(lg[(size_t)img * m + j]);
        if ((key >> L1SHIFT) >= pfx) {
            unsigned pos = atomicAdd(&cnt[task], 1u);
            if (pos < CAP)
                compbuf[(size_t)task * CAP + pos] =
                    ((u64)key << 32) | (unsigned)(~j);
        }
    }
}

// ---------------- pass 4: sort candidates, decode boxes, resort by masked score ----
// Output per-level lists sorted by (masked score desc, orig concat index asc);
// cog[] carries the original within-level rank (= reference top-k position).
__global__ __launch_bounds__(1024) void kSortSelect(
        Ptrs p,
        const unsigned* __restrict__ cnt,
        const u64* __restrict__ compbuf,
        float* __restrict__ cscore,
        float4* __restrict__ cbox,
        float4* __restrict__ cobox,
        float* __restrict__ carea,
        unsigned* __restrict__ cog) {
    int task = blockIdx.x;
    int img = task / NLVL, lvl = task % NLVL;
    __shared__ u64 sortbuf[CAP + 1024];   // 40 KB; phase-2 reused as float farr[10240]
    __shared__ u64 buf2[1024];
    u64* buf = sortbuf;
    int n = min((int)cnt[task], CAP);
    for (int i = threadIdx.x; i < CAP; i += 1024)
        buf[i] = (i < n) ? compbuf[(size_t)task * CAP + i] : 0ULL;
    __syncthreads();
    // bitonic sort, descending by composite ((key<<32)|~idx):
    // value desc, tie -> index asc (matches lax.top_k stability)
    for (int k = 2; k <= CAP; k <<= 1) {
        for (int j2 = k >> 1; j2 > 0; j2 >>= 1) {
            for (int i = threadIdx.x; i < CAP; i += 1024) {
                int pp = i ^ j2;
                if (pp > i) {
                    u64 A = buf[i], B = buf[pp];
                    bool up = ((i & k) == 0);
                    if (up ? (A < B) : (A > B)) { buf[i] = B; buf[pp] = A; }
                }
            }
            __syncthreads();
        }
    }
    const int   MS[5]     = {516096, 129024, 32256, 8064, 2016};
    const int   GW[5]     = {512, 256, 128, 64, 32};
    const float STRIDEF[5]= {4.f, 8.f, 16.f, 32.f, 64.f};
    const int   SIZEI[5]  = {32, 64, 128, 256, 512};
    int r = threadIdx.x;
    float sm = 0.f, x0 = 0.f, y0 = 0.f, x1 = 0.f, y1 = 0.f;
    float b0 = 0.f, b1 = 0.f, b2 = 0.f, b3 = 0.f, area = 0.f;
    if (r < K_TOP) {
        u64 c = buf[r];
        int idx = (int)(~(unsigned)c);
        int m = MS[lvl];
        if ((unsigned)idx >= (unsigned)m) idx = 0;   // safety (never expected)
        const float* lg = p.lg[lvl];
        const float* dl = p.dl[lvl];
        float score = lg[(size_t)img * m + idx];
        int a   = idx % 3;
        int loc = idx / 3;
        int gw  = GW[lvl];
        int x = loc % gw, y = loc / gw;
        // cell anchors: double math then f32 cast, like numpy reference
        double ssz = (double)SIZEI[lvl];
        double arr = (a == 0) ? 0.5 : ((a == 1) ? 1.0 : 2.0);
        double wd = sqrt(ssz * ssz / arr);
        double hd = arr * wd;
        float sx = (float)x * STRIDEF[lvl];
        float sy = (float)y * STRIDEF[lvl];
        float a0 = sx + (float)(-wd * 0.5);
        float a1 = sy + (float)(-hd * 0.5);
        float a2 = sx + (float)( wd * 0.5);
        float a3 = sy + (float)( hd * 0.5);
        float aw = a2 - a0, ah = a3 - a1;
        float acx = a0 + 0.5f * aw, acy = a1 + 0.5f * ah;
        size_t db = ((size_t)img * m + idx) * 4;
        float dx = dl[db], dy = dl[db + 1], dwv = dl[db + 2], dhv = dl[db + 3];
        const float CL = 4.135166556742356f;   // log(1000/16)
        float pw = expf(fminf(dwv, CL)) * aw;
        float ph = expf(fminf(dhv, CL)) * ah;
        float pcx = dx * aw + acx;
        float pcy = dy * ah + acy;
        x0 = pcx - 0.5f * pw; y0 = pcy - 0.5f * ph;
        x1 = pcx + 0.5f * pw; y1 = pcy + 0.5f * ph;
        x0 = fminf(fmaxf(x0, 0.f), 2048.f);
        x1 = fminf(fmaxf(x1, 0.f), 2048.f);
        y0 = fminf(fmaxf(y0, 0.f), 1344.f);
        y1 = fminf(fmaxf(y1, 0.f), 1344.f);
        bool keep = ((x1 - x0) > 0.f) && ((y1 - y0) > 0.f);
        sm = keep ? score : NEGF;
        float off = (float)lvl * 2049.0f;
        b0 = x0 + off; b1 = y0 + off; b2 = x1 + off; b3 = y1 + off;
        area = (b2 - b0) * (b3 - b1);
    }
    __syncthreads();                 // all buf reads done before reuse as farr
    float* farr = (float*)sortbuf;   // [0,1000) score  [1000,2000) area
                                     // [2000,6000) clip box  [6000,10000) offset box
    if (r < K_TOP) {
        farr[r] = sm;
        farr[1000 + r] = area;
        farr[2000 + 4 * r]     = x0;
        farr[2000 + 4 * r + 1] = y0;
        farr[2000 + 4 * r + 2] = x1;
        farr[2000 + 4 * r + 3] = y1;
        farr[6000 + 4 * r]     = b0;
        farr[6000 + 4 * r + 1] = b1;
        farr[6000 + 4 * r + 2] = b2;
        farr[6000 + 4 * r + 3] = b3;
    }
    // composite on MASKED score, tie-break by original concat index (asc)
    buf2[r] = (r < K_TOP)
        ? (((u64)key_of(sm) << 32) | (unsigned)(~(unsigned)(lvl * K_TOP + r)))
        : 0ULL;
    __syncthreads();
    for (int k = 2; k <= 1024; k <<= 1) {
        for (int j2 = k >> 1; j2 > 0; j2 >>= 1) {
            int i = r, pp = i ^ j2;
            if (pp > i) {
                u64 A = buf2[i], B = buf2[pp];
                bool up = ((i & k) == 0);
                if (up ? (A < B) : (A > B)) { buf2[i] = B; buf2[pp] = A; }
            }
            __syncthreads();
        }
    }
    if (r < K_TOP) {
        u64 c2 = buf2[r];
        unsigned g2 = ~(unsigned)c2;
        int rsrc = (int)g2 - lvl * K_TOP;    // original within-level rank
        int ci = img * NCAND + lvl * K_TOP + r;
        cscore[ci] = farr[rsrc];
        carea[ci]  = farr[1000 + rsrc];
        cbox[ci]  = make_float4(farr[2000 + 4 * rsrc],     farr[2000 + 4 * rsrc + 1],
                                farr[2000 + 4 * rsrc + 2], farr[2000 + 4 * rsrc + 3]);
        cobox[ci] = make_float4(farr[6000 + 4 * rsrc],     farr[6000 + 4 * rsrc + 1],
                                farr[6000 + 4 * rsrc + 2], farr[6000 + 4 * rsrc + 3]);
        cog[ci] = (unsigned)rsrc;
    }
}

// ---------------- pass 5a: merge 5 sorted lists into global sorted order ----------------
// Per-level lists are sorted desc by (masked key, orig concat index asc), so
// composite (key<<32)|~orig_g is strictly decreasing within each level.
// rank = pos-in-own-level + sum over other levels of count{composite > mine}.
__global__ __launch_bounds__(1024) void kMerge(
        const float* __restrict__ cscore,
        const float4* __restrict__ cbox,
        const float4* __restrict__ cobox,
        const float* __restrict__ carea,
        const unsigned* __restrict__ cog,
        float* __restrict__ ssc,
        float4* __restrict__ sob,
        float* __restrict__ sar,
        float4* __restrict__ sclip) {
    int img = blockIdx.x;
    __shared__ u64 comp[NCAND];
    for (int g = threadIdx.x; g < NCAND; g += 1024) {
        int lv = g / K_TOP;
        unsigned og = (unsigned)(lv * K_TOP) + cog[img * NCAND + g];
        comp[g] = ((u64)key_of(cscore[img * NCAND + g]) << 32) | (unsigned)(~og);
    }
    __syncthreads();
    for (int g = threadIdx.x; g < NCAND; g += 1024) {
        u64 c = comp[g];
        int lv = g / K_TOP;
        int pos = g - lv * K_TOP;    // elements > c within own (desc-sorted) level
        for (int lv2 = 0; lv2 < NLVL; ++lv2) {
            if (lv2 == lv) continue;
            int base = lv2 * K_TOP;
            int lo = 0, hi = K_TOP;
            while (lo < hi) {
                int mid = (lo + hi) >> 1;
                if (comp[base + mid] > c) lo = mid + 1; else hi = mid;
            }
            pos += lo;               // count of elements > c (composites unique)
        }
        int src = img * NCAND + g;
        int dst = img * NCAND + pos;
        ssc[dst]   = cscore[src];
        sob[dst]   = cobox[src];
        sar[dst]   = carea[src];
        sclip[dst] = cbox[src];
    }
}

// ---------------- pass 5b: bit-packed suppression matrix ----------------
// row i (sorted order), word w: bit b = IoU(i, w*64+b) > 0.7. Only words w >= i>>6 stored.
__global__ __launch_bounds__(256) void kIou(
        const float4* __restrict__ sob,
        const float* __restrict__ sar,
        u64* __restrict__ mat) {
    int img  = blockIdx.y;
    int wid  = threadIdx.x >> 6;
    int lane = threadIdx.x & 63;
    int i = blockIdx.x * 4 + wid;
    if (i >= NCAND) return;
    float4 bi = sob[img * NCAND + i];
    float ari = sar[img * NCAND + i];
    int wstart = i >> 6;
    for (int w = wstart; w < NWORDS; ++w) {
        int j = w * 64 + lane;
        bool pred = false;
        if (j < NCAND) {
            float4 bj = sob[img * NCAND + j];
            float arj = sar[img * NCAND + j];
            float ltx = fmaxf(bj.x, bi.x), lty = fmaxf(bj.y, bi.y);
            float rbx = fminf(bj.z, bi.z), rby = fminf(bj.w, bi.w);
            float wx = fmaxf(rbx - ltx, 0.f), wy = fmaxf(rby - lty, 0.f);
            float inter = wx * wy;
            float denom = (arj + ari) - inter + 1e-9f;
            float iou = inter / denom;
            pred = iou > 0.7f;
        }
        u64 bits = __ballot(pred);
        if (lane == 0) mat[((size_t)(img * NCAND + i)) * RSTRIDE + w] = bits;
    }
}

// ---------------- pass 5c: word-tiled sequential scan (1 wave per image) ----------------
__global__ __launch_bounds__(64) void kScan(
        const float* __restrict__ ssc,
        const float4* __restrict__ sclip,
        const u64* __restrict__ mat,
        float* __restrict__ out) {
    int img  = blockIdx.x;
    int lane = threadIdx.x;
    __shared__ u64 maskS[NWORDS + 1];
    __shared__ u64 diagS[NWORDS * 64];
    __shared__ float sscS[NCAND];
    for (int w = lane; w < NWORDS + 1; w += 64) maskS[w] = 0ULL;
    // preload diagonal 64x64 blocks: diag[w][b] = mat[w*64+b][w]
    for (int it = 0; it < NWORDS; ++it) {
        int i = it * 64 + lane;
        diagS[it * 64 + lane] =
            (i < NCAND) ? mat[((size_t)(img * NCAND + i)) * RSTRIDE + it] : 0ULL;
    }
    for (int idx = lane; idx < NCAND; idx += 64)
        sscS[idx] = ssc[img * NCAND + idx];
    __syncthreads();

    int emitted = 0;
    bool done = false;
    for (int w = 0; w < NWORDS && !done; ++w) {
        u64 cur = ~maskS[w];
        if (w == NWORDS - 1) cur &= (1ULL << (NCAND - (NWORDS - 1) * 64)) - 1ULL;
        while (cur) {
            int b = __builtin_ctzll(cur);
            int i = w * 64 + b;
            float sc = sscS[i];
            if (sc <= -5.0e8f) { done = true; break; }   // all later are invalid too
            if (lane == 0) {
                float4 cb = sclip[img * NCAND + i];
                float* o = out + ((size_t)img * NPOST + emitted) * 5;
                o[0] = cb.x; o[1] = cb.y; o[2] = cb.z; o[3] = cb.w; o[4] = sc;
            }
            ++emitted;
            if (emitted == NPOST) { done = true; break; }
            u64 rw = diagS[w * 64 + b];
            cur &= ~rw;
            cur &= ~(1ULL << b);
            const u64* row = mat + ((size_t)(img * NCAND + i)) * RSTRIDE;
            int w2 = w + 1 + lane;
            if (w2 < NWORDS) maskS[w2] |= row[w2];
            int w3 = w + 65 + lane;
            if (w3 < NWORDS) maskS[w3] |= row[w3];
        }
        __syncthreads();   // make lane ORs visible before reading next mask word
    }
    for (int rr = emitted + lane; rr < NPOST; rr += 64) {
        float* o = out + ((size_t)img * NPOST + rr) * 5;
        o[0] = 0.f; o[1] = 0.f; o[2] = 0.f; o[3] = 0.f; o[4] = NEGF;
    }
}

// ---------------- fallback: round-1 sequential NMS (used only if ws too small) ----------------
__global__ __launch_bounds__(1024) void kNMS(
        const float* __restrict__ cscore,
        const float4* __restrict__ cbox,
        const float4* __restrict__ cobox,
        const float* __restrict__ carea,
        float* __restrict__ out) {
    int img = blockIdx.x;
    int tid = threadIdx.x;
    __shared__ u64 warr[16];
    __shared__ float bb[5];
    float s[5], b0[5], b1[5], b2[5], b3[5], ar[5];
#pragma unroll
    for (int k = 0; k < 5; ++k) {
        int j = tid + k * 1024;
        if (j < NCAND) {
            int ci = img * NCAND + j;
            s[k] = cscore[ci];
            float4 b = cobox[ci];
            b0[k] = b.x; b1[k] = b.y; b2[k] = b.z; b3[k] = b.w;
            ar[k] = carea[ci];
        } else {
            s[k] = -3.4e38f;
            b0[k] = b1[k] = b2[k] = b3[k] = 0.f; ar[k] = 0.f;
        }
    }
    for (int step = 0; step < NPOST; ++step) {
        u64 comp = 0ULL;
#pragma unroll
        for (int k = 0; k < 5; ++k) {
            int j = tid + k * 1024;
            unsigned kk = key_of(s[k]);
            u64 c = ((u64)kk << 32) | (unsigned)(~j);
            comp = (c > comp) ? c : comp;
        }
#pragma unroll
        for (int off2 = 32; off2 >= 1; off2 >>= 1) {
            u64 o = __shfl_xor(comp, off2, 64);
            comp = (o > comp) ? o : comp;
        }
        if ((tid & 63) == 0) warr[tid >> 6] = comp;
        __syncthreads();
        u64 best = warr[0];
#pragma unroll
        for (int w = 1; w < 16; ++w) {
            u64 o = warr[w];
            best = (o > best) ? o : best;
        }
        int bidx = (int)(~(unsigned)best);
        float bscore = key_to_float((unsigned)(best >> 32));
        bool valid = bscore > -5.0e8f;
#pragma unroll
        for (int k = 0; k < 5; ++k) {
            int j = tid + k * 1024;
            if (j == bidx) {
                bb[0] = b0[k]; bb[1] = b1[k]; bb[2] = b2[k]; bb[3] = b3[k]; bb[4] = ar[k];
                float* o = out + ((size_t)img * NPOST + step) * 5;
                if (valid) {
                    float4 gb = cbox[img * NCAND + j];
                    o[0] = gb.x; o[1] = gb.y; o[2] = gb.z; o[3] = gb.w; o[4] = bscore;
                } else {
                    o[0] = 0.f; o[1] = 0.f; o[2] = 0.f; o[3] = 0.f; o[4] = NEGF;
                }
            }
        }
        __syncthreads();
        float ib0 = bb[0], ib1 = bb[1], ib2 = bb[2], ib3 = bb[3], iar = bb[4];
#pragma unroll
        for (int k = 0; k < 5; ++k) {
            int j = tid + k * 1024;
            float ltx = fmaxf(b0[k], ib0), lty = fmaxf(b1[k], ib1);
            float rbx = fminf(b2[k], ib2), rby = fminf(b3[k], ib3);
            float wx = fmaxf(rbx - ltx, 0.f), wy = fmaxf(rby - lty, 0.f);
            float inter = wx * wy;
            float denom = ar[k] + iar;
            denom = denom - inter;
            denom = denom + 1e-9f;
            float iou = inter / denom;
            if (iou > 0.7f) s[k] = NEGF;
            if (j == bidx) s[k] = NEGF;
        }
    }
}

extern "C" void kernel_launch(void* const* d_in, const int* in_sizes, int n_in,
                              void* d_out, int out_size, void* d_ws, size_t ws_size,
                              hipStream_t stream) {
    const int MS[5] = {516096, 129024, 32256, 8064, 2016};
    Ptrs P;
    for (int l = 0; l < 5; ++l) {
        P.lg[l] = (const float*)d_in[2 * l];
        P.dl[l] = (const float*)d_in[2 * l + 1];
    }
    char* w = (char*)d_ws;
    size_t off = 0;
    auto alloc = [&](size_t bytes) -> void* {
        void* pp = (void*)(w + off);
        off = (off + bytes + 255) & ~(size_t)255;
        return pp;
    };
    unsigned* hist  = (unsigned*)alloc((size_t)NTASK * NB1 * 4);
    unsigned* tinfo = (unsigned*)alloc(NTASK * 2 * 4);
    unsigned* cnt   = (unsigned*)alloc(NTASK * 4);
    u64* compb      = (u64*)alloc((size_t)NTASK * CAP * 8);
    float*  cscore  = (float*)alloc((size_t)NTASK * K_TOP * 4);
    float4* cbox    = (float4*)alloc((size_t)NTASK * K_TOP * 16);
    float4* cobox   = (float4*)alloc((size_t)NTASK * K_TOP * 16);
    float*  carea   = (float*)alloc((size_t)NTASK * K_TOP * 4);
    unsigned* cog   = (unsigned*)alloc((size_t)NTASK * K_TOP * 4);
    // NMS scratch
    float*  ssc     = (float*)alloc((size_t)NIMG * NCAND * 4);
    float4* sob     = (float4*)alloc((size_t)NIMG * NCAND * 16);
    float*  sar     = (float*)alloc((size_t)NIMG * NCAND * 4);
    float4* sclip   = (float4*)alloc((size_t)NIMG * NCAND * 16);
    u64*    mat     = (u64*)alloc((size_t)NIMG * NCAND * RSTRIDE * 8);
    size_t need = off;
    (void)in_sizes; (void)n_in; (void)out_size;

    size_t nhz = (size_t)NTASK * NB1;
    kZero<<<2048, 256, 0, stream>>>(hist, nhz);
    for (int l = 0; l < 5; ++l) {
        int m4 = MS[l] >> 2;
        int gx = (m4 + 8191) / 8192;       // ~32K elements per block
        dim3 g(gx, NIMG);
        kHist<<<g, 1024, 0, stream>>>(P.lg[l], MS[l], l, hist);
    }
    kSelectBin<<<NTASK, 256, 0, stream>>>(hist, tinfo, cnt);
    for (int l = 0; l < 5; ++l) {
        dim3 g((MS[l] + 255) / 256, NIMG);
        kCompact<<<g, 256, 0, stream>>>(P.lg[l], MS[l], l, tinfo, cnt, compb);
    }
    kSortSelect<<<NTASK, 1024, 0, stream>>>(P, cnt, compb, cscore, cbox, cobox, carea, cog);

    if (ws_size >= need) {
        kMerge<<<NIMG, 1024, 0, stream>>>(cscore, cbox, cobox, carea, cog,
                                          ssc, sob, sar, sclip);
        dim3 gi((NCAND + 3) / 4, NIMG);
        kIou<<<gi, 256, 0, stream>>>(sob, sar, mat);
        kScan<<<NIMG, 64, 0, stream>>>(ssc, sclip, mat, (float*)d_out);
    } else {
        kNMS<<<NIMG, 1024, 0, stream>>>(cscore, cbox, cobox, carea, (float*)d_out);
    }
}

// Round 5
// 564.311 us; speedup vs baseline: 3.4582x; 1.1156x over previous
//
#include <hip/hip_runtime.h>
#include <cstdint>
#include <cstddef>

#define NB1      16384      // 2^14 first-level radix bins
#define L1SHIFT  18         // key >> 18 -> 14-bit bin
#define CAP      4096       // compaction buffer per task (power of 2 for bitonic)
#define K_TOP    1000
#define NCAND    5000
#define NIMG     8
#define NLVL     5
#define NTASK    40
#define NPOST    300
#define NEGF     (-1e9f)
#define NWORDS   79         // ceil(5000/64)
#define RSTRIDE  80         // u64 row stride for suppression matrix

typedef unsigned long long u64;

struct Ptrs {
    const float* lg[5];
    const float* dl[5];
};

__device__ __forceinline__ unsigned key_of(float f) {
    unsigned u = __float_as_uint(f);
    return (u & 0x80000000u) ? ~u : (u | 0x80000000u);
}
__device__ __forceinline__ float key_to_float(unsigned k) {
    unsigned u = (k & 0x80000000u) ? (k ^ 0x80000000u) : ~k;
    return __uint_as_float(u);
}

// ---------------- zero scratch ----------------
__global__ void kZero(unsigned* p, size_t n) {
    size_t i = (size_t)blockIdx.x * blockDim.x + threadIdx.x;
    size_t st = (size_t)gridDim.x * blockDim.x;
    for (; i < n; i += st) p[i] = 0u;
}

// ---------------- pass 1: LDS-privatized 14-bit histogram per (img,lvl) ----------------
__global__ __launch_bounds__(1024) void kHist(const float* __restrict__ lg,
                                              int m, int lvl,
                                              unsigned* __restrict__ hist) {
    int img  = blockIdx.y;
    int task = img * NLVL + lvl;
    __shared__ unsigned h[NB1];
    for (int i = threadIdx.x; i < NB1; i += 1024) h[i] = 0u;
    __syncthreads();
    int m4 = m >> 2;                       // all level sizes divisible by 4
    int chunk4 = (m4 + gridDim.x - 1) / (int)gridDim.x;
    int start4 = blockIdx.x * chunk4;
    int end4   = min(start4 + chunk4, m4);
    const float4* src = (const float4*)(lg + (size_t)img * m);
    for (int i = start4 + threadIdx.x; i < end4; i += 1024) {
        float4 v = src[i];
        atomicAdd(&h[key_of(v.x) >> L1SHIFT], 1u);
        atomicAdd(&h[key_of(v.y) >> L1SHIFT], 1u);
        atomicAdd(&h[key_of(v.z) >> L1SHIFT], 1u);
        atomicAdd(&h[key_of(v.w) >> L1SHIFT], 1u);
    }
    __syncthreads();
    unsigned* gh = hist + (size_t)task * NB1;
    for (int i = threadIdx.x; i < NB1; i += 1024) {
        unsigned c = h[i];
        if (c) atomicAdd(&gh[i], c);
    }
}

// ---------------- pass 2: find 14-bit prefix of the K-th largest ----------------
__global__ __launch_bounds__(256) void kSelectBin(const unsigned* __restrict__ hist,
                                                  unsigned* __restrict__ tinfo,
                                                  unsigned* __restrict__ cnt) {
    int task = blockIdx.x;
    const unsigned* h = hist + (size_t)task * NB1;
    __shared__ unsigned sblk[256];
    __shared__ unsigned sbin[64];
    __shared__ int sh_tb;
    __shared__ unsigned sh_rem;
    int t = threadIdx.x;
    unsigned s = 0;
    for (int i = 0; i < 64; ++i) s += h[t * 64 + i];
    sblk[t] = s;
    __syncthreads();
    if (t == 0) {
        unsigned rem = K_TOP; int tb = 0;
        for (int b = 255; b >= 0; --b) {
            if (sblk[b] < rem) rem -= sblk[b];
            else { tb = b; break; }
        }
        sh_tb = tb; sh_rem = rem;
    }
    __syncthreads();
    if (t < 64) sbin[t] = h[sh_tb * 64 + t];
    __syncthreads();
    if (t == 0) {
        unsigned rem = sh_rem; int pfx = sh_tb * 64;
        for (int b = 63; b >= 0; --b) {
            if (sbin[b] < rem) rem -= sbin[b];
            else { pfx = sh_tb * 64 + b; break; }
        }
        tinfo[task * 2]     = (unsigned)pfx;
        tinfo[task * 2 + 1] = rem;
        cnt[task] = 0u;
    }
}

// ---------------- pass 3: compact all keys with bin >= prefix ----------------
__global__ void kCompact(const float* __restrict__ lg, int m, int lvl,
                         const unsigned* __restrict__ tinfo,
                         unsigned* __restrict__ cnt,
                         u64* __restrict__ compbuf) {
    int img = blockIdx.y;
    int task = img * NLVL + lvl;
    unsigned pfx = tinfo[task * 2];
    int j = blockIdx.x * blockDim.x + threadIdx.x;
    if (j < m) {
        unsigned key = key_of(lg[(size_t)img * m + j]);
        if ((key >> L1SHIFT) >= pfx) {
            unsigned pos = atomicAdd(&cnt[task], 1u);
            if (pos < CAP)
                compbuf[(size_t)task * CAP + pos] =
                    ((u64)key << 32) | (unsigned)(~j);
        }
    }
}

// ---------------- pass 4: sort candidates, decode boxes, resort by masked score ----
__global__ __launch_bounds__(1024) void kSortSelect(
        Ptrs p,
        const unsigned* __restrict__ cnt,
        const u64* __restrict__ compbuf,
        float* __restrict__ cscore,
        float4* __restrict__ cbox,
        float4* __restrict__ cobox,
        float* __restrict__ carea,
        unsigned* __restrict__ cog) {
    int task = blockIdx.x;
    int img = task / NLVL, lvl = task % NLVL;
    __shared__ u64 sortbuf[CAP + 1024];   // 40 KB; phase-2 reused as float farr[10240]
    __shared__ u64 buf2[1024];
    u64* buf = sortbuf;
    int n = min((int)cnt[task], CAP);
    for (int i = threadIdx.x; i < CAP; i += 1024)
        buf[i] = (i < n) ? compbuf[(size_t)task * CAP + i] : 0ULL;
    __syncthreads();
    for (int k = 2; k <= CAP; k <<= 1) {
        for (int j2 = k >> 1; j2 > 0; j2 >>= 1) {
            for (int i = threadIdx.x; i < CAP; i += 1024) {
                int pp = i ^ j2;
                if (pp > i) {
                    u64 A = buf[i], B = buf[pp];
                    bool up = ((i & k) == 0);
                    if (up ? (A < B) : (A > B)) { buf[i] = B; buf[pp] = A; }
                }
            }
            __syncthreads();
        }
    }
    const int   MS[5]     = {516096, 129024, 32256, 8064, 2016};
    const int   GW[5]     = {512, 256, 128, 64, 32};
    const float STRIDEF[5]= {4.f, 8.f, 16.f, 32.f, 64.f};
    const int   SIZEI[5]  = {32, 64, 128, 256, 512};
    int r = threadIdx.x;
    float sm = 0.f, x0 = 0.f, y0 = 0.f, x1 = 0.f, y1 = 0.f;
    float b0 = 0.f, b1 = 0.f, b2 = 0.f, b3 = 0.f, area = 0.f;
    if (r < K_TOP) {
        u64 c = buf[r];
        int idx = (int)(~(unsigned)c);
        int m = MS[lvl];
        if ((unsigned)idx >= (unsigned)m) idx = 0;   // safety (never expected)
        const float* lg = p.lg[lvl];
        const float* dl = p.dl[lvl];
        float score = lg[(size_t)img * m + idx];
        int a   = idx % 3;
        int loc = idx / 3;
        int gw  = GW[lvl];
        int x = loc % gw, y = loc / gw;
        double ssz = (double)SIZEI[lvl];
        double arr = (a == 0) ? 0.5 : ((a == 1) ? 1.0 : 2.0);
        double wd = sqrt(ssz * ssz / arr);
        double hd = arr * wd;
        float sx = (float)x * STRIDEF[lvl];
        float sy = (float)y * STRIDEF[lvl];
        float a0 = sx + (float)(-wd * 0.5);
        float a1 = sy + (float)(-hd * 0.5);
        float a2 = sx + (float)( wd * 0.5);
        float a3 = sy + (float)( hd * 0.5);
        float aw = a2 - a0, ah = a3 - a1;
        float acx = a0 + 0.5f * aw, acy = a1 + 0.5f * ah;
        size_t db = ((size_t)img * m + idx) * 4;
        float dx = dl[db], dy = dl[db + 1], dwv = dl[db + 2], dhv = dl[db + 3];
        const float CL = 4.135166556742356f;   // log(1000/16)
        float pw = expf(fminf(dwv, CL)) * aw;
        float ph = expf(fminf(dhv, CL)) * ah;
        float pcx = dx * aw + acx;
        float pcy = dy * ah + acy;
        x0 = pcx - 0.5f * pw; y0 = pcy - 0.5f * ph;
        x1 = pcx + 0.5f * pw; y1 = pcy + 0.5f * ph;
        x0 = fminf(fmaxf(x0, 0.f), 2048.f);
        x1 = fminf(fmaxf(x1, 0.f), 2048.f);
        y0 = fminf(fmaxf(y0, 0.f), 1344.f);
        y1 = fminf(fmaxf(y1, 0.f), 1344.f);
        bool keep = ((x1 - x0) > 0.f) && ((y1 - y0) > 0.f);
        sm = keep ? score : NEGF;
        float off = (float)lvl * 2049.0f;
        b0 = x0 + off; b1 = y0 + off; b2 = x1 + off; b3 = y1 + off;
        area = (b2 - b0) * (b3 - b1);
    }
    __syncthreads();                 // all buf reads done before reuse as farr
    float* farr = (float*)sortbuf;   // [0,1000) score  [1000,2000) area
                                     // [2000,6000) clip box  [6000,10000) offset box
    if (r < K_TOP) {
        farr[r] = sm;
        farr[1000 + r] = area;
        farr[2000 + 4 * r]     = x0;
        farr[2000 + 4 * r + 1] = y0;
        farr[2000 + 4 * r + 2] = x1;
        farr[2000 + 4 * r + 3] = y1;
        farr[6000 + 4 * r]     = b0;
        farr[6000 + 4 * r + 1] = b1;
        farr[6000 + 4 * r + 2] = b2;
        farr[6000 + 4 * r + 3] = b3;
    }
    buf2[r] = (r < K_TOP)
        ? (((u64)key_of(sm) << 32) | (unsigned)(~(unsigned)(lvl * K_TOP + r)))
        : 0ULL;
    __syncthreads();
    for (int k = 2; k <= 1024; k <<= 1) {
        for (int j2 = k >> 1; j2 > 0; j2 >>= 1) {
            int i = r, pp = i ^ j2;
            if (pp > i) {
                u64 A = buf2[i], B = buf2[pp];
                bool up = ((i & k) == 0);
                if (up ? (A < B) : (A > B)) { buf2[i] = B; buf2[pp] = A; }
            }
            __syncthreads();
        }
    }
    if (r < K_TOP) {
        u64 c2 = buf2[r];
        unsigned g2 = ~(unsigned)c2;
        int rsrc = (int)g2 - lvl * K_TOP;    // original within-level rank
        int ci = img * NCAND + lvl * K_TOP + r;
        cscore[ci] = farr[rsrc];
        carea[ci]  = farr[1000 + rsrc];
        cbox[ci]  = make_float4(farr[2000 + 4 * rsrc],     farr[2000 + 4 * rsrc + 1],
                                farr[2000 + 4 * rsrc + 2], farr[2000 + 4 * rsrc + 3]);
        cobox[ci] = make_float4(farr[6000 + 4 * rsrc],     farr[6000 + 4 * rsrc + 1],
                                farr[6000 + 4 * rsrc + 2], farr[6000 + 4 * rsrc + 3]);
        cog[ci] = (unsigned)rsrc;
    }
}

// ---------------- pass 5a: merge 5 sorted lists into global sorted order ----------------
__global__ __launch_bounds__(1024) void kMerge(
        const float* __restrict__ cscore,
        const float4* __restrict__ cbox,
        const float4* __restrict__ cobox,
        const float* __restrict__ carea,
        const unsigned* __restrict__ cog,
        float* __restrict__ ssc,
        float4* __restrict__ sob,
        float* __restrict__ sar,
        float4* __restrict__ sclip) {
    int img = blockIdx.x;
    __shared__ u64 comp[NCAND];
    for (int g = threadIdx.x; g < NCAND; g += 1024) {
        int lv = g / K_TOP;
        unsigned og = (unsigned)(lv * K_TOP) + cog[img * NCAND + g];
        comp[g] = ((u64)key_of(cscore[img * NCAND + g]) << 32) | (unsigned)(~og);
    }
    __syncthreads();
    for (int g = threadIdx.x; g < NCAND; g += 1024) {
        u64 c = comp[g];
        int lv = g / K_TOP;
        int pos = g - lv * K_TOP;    // elements > c within own (desc-sorted) level
        for (int lv2 = 0; lv2 < NLVL; ++lv2) {
            if (lv2 == lv) continue;
            int base = lv2 * K_TOP;
            int lo = 0, hi = K_TOP;
            while (lo < hi) {
                int mid = (lo + hi) >> 1;
                if (comp[base + mid] > c) lo = mid + 1; else hi = mid;
            }
            pos += lo;               // count of elements > c (composites unique)
        }
        int src = img * NCAND + g;
        int dst = img * NCAND + pos;
        ssc[dst]   = cscore[src];
        sob[dst]   = cobox[src];
        sar[dst]   = carea[src];
        sclip[dst] = cbox[src];
    }
}

// ---------------- pass 5b: bit-packed suppression matrix ----------------
__global__ __launch_bounds__(256) void kIou(
        const float4* __restrict__ sob,
        const float* __restrict__ sar,
        u64* __restrict__ mat) {
    int img  = blockIdx.y;
    int wid  = threadIdx.x >> 6;
    int lane = threadIdx.x & 63;
    int i = blockIdx.x * 4 + wid;
    if (i >= NCAND) return;
    float4 bi = sob[img * NCAND + i];
    float ari = sar[img * NCAND + i];
    int wstart = i >> 6;
    for (int w = wstart; w < NWORDS; ++w) {
        int j = w * 64 + lane;
        bool pred = false;
        if (j < NCAND) {
            float4 bj = sob[img * NCAND + j];
            float arj = sar[img * NCAND + j];
            float ltx = fmaxf(bj.x, bi.x), lty = fmaxf(bj.y, bi.y);
            float rbx = fminf(bj.z, bi.z), rby = fminf(bj.w, bi.w);
            float wx = fmaxf(rbx - ltx, 0.f), wy = fmaxf(rby - lty, 0.f);
            float inter = wx * wy;
            float denom = (arj + ari) - inter + 1e-9f;
            float iou = inter / denom;
            pred = iou > 0.7f;
        }
        u64 bits = __ballot(pred);
        if (lane == 0) mat[((size_t)(img * NCAND + i)) * RSTRIDE + w] = bits;
    }
}

// ---------------- pass 5c: word-tiled scan with deferred batched row-OR ----------------
// Per emission: suppression within the current word comes from LDS diagS only;
// the row-OR into future mask words is deferred to the word boundary and done
// as a batched load (independent loads -> one latency per word, not per box).
__global__ __launch_bounds__(64) void kScan(
        const float* __restrict__ ssc,
        const float4* __restrict__ sclip,
        const u64* __restrict__ mat,
        float* __restrict__ out) {
    int img  = blockIdx.x;
    int lane = threadIdx.x;
    __shared__ u64 maskS[NWORDS + 1];
    __shared__ u64 diagS[NWORDS * 64];
    __shared__ float sscS[NCAND];
    __shared__ unsigned pendS[64];
    for (int w = lane; w < NWORDS + 1; w += 64) maskS[w] = 0ULL;
    // preload diagonal 64x64 blocks: diag[w][b] = mat[w*64+b][w]
    for (int it = 0; it < NWORDS; ++it) {
        int i = it * 64 + lane;
        diagS[it * 64 + lane] =
            (i < NCAND) ? mat[((size_t)(img * NCAND + i)) * RSTRIDE + it] : 0ULL;
    }
    for (int idx = lane; idx < NCAND; idx += 64)
        sscS[idx] = ssc[img * NCAND + idx];
    __syncthreads();

    const u64* matI = mat + (size_t)img * NCAND * RSTRIDE;
    int emitted = 0;
    bool done = false;
    for (int w = 0; w < NWORDS && !done; ++w) {
        u64 cur = ~maskS[w];
        if (w == NWORDS - 1) cur &= (1ULL << (NCAND - (NWORDS - 1) * 64)) - 1ULL;
        int npend = 0;
        while (cur) {
            int b = __builtin_ctzll(cur);
            int i = w * 64 + b;
            float sc = sscS[i];
            if (sc <= -5.0e8f) { done = true; break; }   // all later are invalid too
            if (lane == 0) {
                float4 cb = sclip[img * NCAND + i];
                float* o = out + ((size_t)img * NPOST + emitted) * 5;
                o[0] = cb.x; o[1] = cb.y; o[2] = cb.z; o[3] = cb.w; o[4] = sc;
            }
            ++emitted;
            if (emitted == NPOST) { done = true; break; }
            u64 rw = diagS[w * 64 + b];       // same-word suppression (LDS, fast)
            cur &= ~rw;
            cur &= ~(1ULL << b);
            if (lane == 0) pendS[npend] = (unsigned)i;
            ++npend;                          // wave-uniform
        }
        if (!done && npend) {
            __syncthreads();                  // pendS visible (1 wave: just a waitcnt)
            int w2 = w + 1 + lane;            // lanes cover w+1 .. w+128 >= NWORDS
            int w3 = w + 65 + lane;
            bool v2 = (w2 < NWORDS), v3 = (w3 < NWORDS);
            u64 acc2 = 0, acc3 = 0;
            int k0 = 0;
            for (; k0 + 4 <= npend; k0 += 4) {  // 8 independent loads per chunk
                const u64* r0 = matI + (size_t)pendS[k0 + 0] * RSTRIDE;
                const u64* r1 = matI + (size_t)pendS[k0 + 1] * RSTRIDE;
                const u64* r2 = matI + (size_t)pendS[k0 + 2] * RSTRIDE;
                const u64* r3 = matI + (size_t)pendS[k0 + 3] * RSTRIDE;
                u64 a0 = 0, a1 = 0, a2 = 0, a3 = 0, c0 = 0, c1 = 0, c2 = 0, c3 = 0;
                if (v2) { a0 = r0[w2]; a1 = r1[w2]; a2 = r2[w2]; a3 = r3[w2]; }
                if (v3) { c0 = r0[w3]; c1 = r1[w3]; c2 = r2[w3]; c3 = r3[w3]; }
                acc2 |= (a0 | a1) | (a2 | a3);
                acc3 |= (c0 | c1) | (c2 | c3);
            }
            for (; k0 < npend; ++k0) {
                const u64* r = matI + (size_t)pendS[k0] * RSTRIDE;
                if (v2) acc2 |= r[w2];
                if (v3) acc3 |= r[w3];
            }
            if (v2) maskS[w2] |= acc2;        // distinct word per lane: no conflicts
            if (v3) maskS[w3] |= acc3;
        }
        __syncthreads();
    }
    for (int rr = emitted + lane; rr < NPOST; rr += 64) {
        float* o = out + ((size_t)img * NPOST + rr) * 5;
        o[0] = 0.f; o[1] = 0.f; o[2] = 0.f; o[3] = 0.f; o[4] = NEGF;
    }
}

// ---------------- fallback: round-1 sequential NMS (used only if ws too small) ----------------
__global__ __launch_bounds__(1024) void kNMS(
        const float* __restrict__ cscore,
        const float4* __restrict__ cbox,
        const float4* __restrict__ cobox,
        const float* __restrict__ carea,
        float* __restrict__ out) {
    int img = blockIdx.x;
    int tid = threadIdx.x;
    __shared__ u64 warr[16];
    __shared__ float bb[5];
    float s[5], b0[5], b1[5], b2[5], b3[5], ar[5];
#pragma unroll
    for (int k = 0; k < 5; ++k) {
        int j = tid + k * 1024;
        if (j < NCAND) {
            int ci = img * NCAND + j;
            s[k] = cscore[ci];
            float4 b = cobox[ci];
            b0[k] = b.x; b1[k] = b.y; b2[k] = b.z; b3[k] = b.w;
            ar[k] = carea[ci];
        } else {
            s[k] = -3.4e38f;
            b0[k] = b1[k] = b2[k] = b3[k] = 0.f; ar[k] = 0.f;
        }
    }
    for (int step = 0; step < NPOST; ++step) {
        u64 comp = 0ULL;
#pragma unroll
        for (int k = 0; k < 5; ++k) {
            int j = tid + k * 1024;
            unsigned kk = key_of(s[k]);
            u64 c = ((u64)kk << 32) | (unsigned)(~j);
            comp = (c > comp) ? c : comp;
        }
#pragma unroll
        for (int off2 = 32; off2 >= 1; off2 >>= 1) {
            u64 o = __shfl_xor(comp, off2, 64);
            comp = (o > comp) ? o : comp;
        }
        if ((tid & 63) == 0) warr[tid >> 6] = comp;
        __syncthreads();
        u64 best = warr[0];
#pragma unroll
        for (int w = 1; w < 16; ++w) {
            u64 o = warr[w];
            best = (o > best) ? o : best;
        }
        int bidx = (int)(~(unsigned)best);
        float bscore = key_to_float((unsigned)(best >> 32));
        bool valid = bscore > -5.0e8f;
#pragma unroll
        for (int k = 0; k < 5; ++k) {
            int j = tid + k * 1024;
            if (j == bidx) {
                bb[0] = b0[k]; bb[1] = b1[k]; bb[2] = b2[k]; bb[3] = b3[k]; bb[4] = ar[k];
                float* o = out + ((size_t)img * NPOST + step) * 5;
                if (valid) {
                    float4 gb = cbox[img * NCAND + j];
                    o[0] = gb.x; o[1] = gb.y; o[2] = gb.z; o[3] = gb.w; o[4] = bscore;
                } else {
                    o[0] = 0.f; o[1] = 0.f; o[2] = 0.f; o[3] = 0.f; o[4] = NEGF;
                }
            }
        }
        __syncthreads();
        float ib0 = bb[0], ib1 = bb[1], ib2 = bb[2], ib3 = bb[3], iar = bb[4];
#pragma unroll
        for (int k = 0; k < 5; ++k) {
            int j = tid + k * 1024;
            float ltx = fmaxf(b0[k], ib0), lty = fmaxf(b1[k], ib1);
            float rbx = fminf(b2[k], ib2), rby = fminf(b3[k], ib3);
            float wx = fmaxf(rbx - ltx, 0.f), wy = fmaxf(rby - lty, 0.f);
            float inter = wx * wy;
            float denom = ar[k] + iar;
            denom = denom - inter;
            denom = denom + 1e-9f;
            float iou = inter / denom;
            if (iou > 0.7f) s[k] = NEGF;
            if (j == bidx) s[k] = NEGF;
        }
    }
}

extern "C" void kernel_launch(void* const* d_in, const int* in_sizes, int n_in,
                              void* d_out, int out_size, void* d_ws, size_t ws_size,
                              hipStream_t stream) {
    const int MS[5] = {516096, 129024, 32256, 8064, 2016};
    Ptrs P;
    for (int l = 0; l < 5; ++l) {
        P.lg[l] = (const float*)d_in[2 * l];
        P.dl[l] = (const float*)d_in[2 * l + 1];
    }
    char* w = (char*)d_ws;
    size_t off = 0;
    auto alloc = [&](size_t bytes) -> void* {
        void* pp = (void*)(w + off);
        off = (off + bytes + 255) & ~(size_t)255;
        return pp;
    };
    unsigned* hist  = (unsigned*)alloc((size_t)NTASK * NB1 * 4);
    unsigned* tinfo = (unsigned*)alloc(NTASK * 2 * 4);
    unsigned* cnt   = (unsigned*)alloc(NTASK * 4);
    u64* compb      = (u64*)alloc((size_t)NTASK * CAP * 8);
    float*  cscore  = (float*)alloc((size_t)NTASK * K_TOP * 4);
    float4* cbox    = (float4*)alloc((size_t)NTASK * K_TOP * 16);
    float4* cobox   = (float4*)alloc((size_t)NTASK * K_TOP * 16);
    float*  carea   = (float*)alloc((size_t)NTASK * K_TOP * 4);
    unsigned* cog   = (unsigned*)alloc((size_t)NTASK * K_TOP * 4);
    // NMS scratch
    float*  ssc     = (float*)alloc((size_t)NIMG * NCAND * 4);
    float4* sob     = (float4*)alloc((size_t)NIMG * NCAND * 16);
    float*  sar     = (float*)alloc((size_t)NIMG * NCAND * 4);
    float4* sclip   = (float4*)alloc((size_t)NIMG * NCAND * 16);
    u64*    mat     = (u64*)alloc((size_t)NIMG * NCAND * RSTRIDE * 8);
    size_t need = off;
    (void)in_sizes; (void)n_in; (void)out_size;

    size_t nhz = (size_t)NTASK * NB1;
    kZero<<<2048, 256, 0, stream>>>(hist, nhz);
    for (int l = 0; l < 5; ++l) {
        int m4 = MS[l] >> 2;
        int gx = (m4 + 8191) / 8192;       // ~32K elements per block
        dim3 g(gx, NIMG);
        kHist<<<g, 1024, 0, stream>>>(P.lg[l], MS[l], l, hist);
    }
    kSelectBin<<<NTASK, 256, 0, stream>>>(hist, tinfo, cnt);
    for (int l = 0; l < 5; ++l) {
        dim3 g((MS[l] + 255) / 256, NIMG);
        kCompact<<<g, 256, 0, stream>>>(P.lg[l], MS[l], l, tinfo, cnt, compb);
    }
    kSortSelect<<<NTASK, 1024, 0, stream>>>(P, cnt, compb, cscore, cbox, cobox, carea, cog);

    if (ws_size >= need) {
        kMerge<<<NIMG, 1024, 0, stream>>>(cscore, cbox, cobox, carea, cog,
                                          ssc, sob, sar, sclip);
        dim3 gi((NCAND + 3) / 4, NIMG);
        kIou<<<gi, 256, 0, stream>>>(sob, sar, mat);
        kScan<<<NIMG, 64, 0, stream>>>(ssc, sclip, mat, (float*)d_out);
    } else {
        kNMS<<<NIMG, 1024, 0, stream>>>(cscore, cbox, cobox, carea, (float*)d_out);
    }
}

// Round 6
// 536.389 us; speedup vs baseline: 3.6383x; 1.0521x over previous
//
#include <hip/hip_runtime.h>
#include <cstdint>
#include <cstddef>

#define NB1      16384      // 2^14 first-level radix bins
#define L1SHIFT  18         // key >> 18 -> 14-bit bin
#define CAP      4096       // compaction buffer per task (power of 2 for bitonic)
#define K_TOP    1000
#define NCAND    5000
#define NIMG     8
#define NLVL     5
#define NTASK    40
#define NPOST    300
#define NEGF     (-1e9f)
#define NWORDS   79         // ceil(5000/64)
#define RSTRIDE  80         // u64 row stride for suppression matrix

typedef unsigned long long u64;

struct Ptrs {
    const float* lg[5];
    const float* dl[5];
};

__device__ __forceinline__ unsigned key_of(float f) {
    unsigned u = __float_as_uint(f);
    return (u & 0x80000000u) ? ~u : (u | 0x80000000u);
}
__device__ __forceinline__ float key_to_float(unsigned k) {
    unsigned u = (k & 0x80000000u) ? (k ^ 0x80000000u) : ~k;
    return __uint_as_float(u);
}

// ---------------- zero scratch ----------------
__global__ void kZero(unsigned* p, size_t n) {
    size_t i = (size_t)blockIdx.x * blockDim.x + threadIdx.x;
    size_t st = (size_t)gridDim.x * blockDim.x;
    for (; i < n; i += st) p[i] = 0u;
}

// ---------------- pass 1: LDS-privatized 14-bit histogram per (img,lvl) ----------------
__global__ __launch_bounds__(1024) void kHist(const float* __restrict__ lg,
                                              int m, int lvl,
                                              unsigned* __restrict__ hist) {
    int img  = blockIdx.y;
    int task = img * NLVL + lvl;
    __shared__ unsigned h[NB1];
    for (int i = threadIdx.x; i < NB1; i += 1024) h[i] = 0u;
    __syncthreads();
    int m4 = m >> 2;                       // all level sizes divisible by 4
    int chunk4 = (m4 + gridDim.x - 1) / (int)gridDim.x;
    int start4 = blockIdx.x * chunk4;
    int end4   = min(start4 + chunk4, m4);
    const float4* src = (const float4*)(lg + (size_t)img * m);
    for (int i = start4 + threadIdx.x; i < end4; i += 1024) {
        float4 v = src[i];
        atomicAdd(&h[key_of(v.x) >> L1SHIFT], 1u);
        atomicAdd(&h[key_of(v.y) >> L1SHIFT], 1u);
        atomicAdd(&h[key_of(v.z) >> L1SHIFT], 1u);
        atomicAdd(&h[key_of(v.w) >> L1SHIFT], 1u);
    }
    __syncthreads();
    unsigned* gh = hist + (size_t)task * NB1;
    for (int i = threadIdx.x; i < NB1; i += 1024) {
        unsigned c = h[i];
        if (c) atomicAdd(&gh[i], c);
    }
}

// ---------------- pass 2: find 14-bit prefix of the K-th largest ----------------
__global__ __launch_bounds__(256) void kSelectBin(const unsigned* __restrict__ hist,
                                                  unsigned* __restrict__ tinfo,
                                                  unsigned* __restrict__ cnt) {
    int task = blockIdx.x;
    const unsigned* h = hist + (size_t)task * NB1;
    __shared__ unsigned sblk[256];
    __shared__ unsigned sbin[64];
    __shared__ int sh_tb;
    __shared__ unsigned sh_rem;
    int t = threadIdx.x;
    unsigned s = 0;
    for (int i = 0; i < 64; ++i) s += h[t * 64 + i];
    sblk[t] = s;
    __syncthreads();
    if (t == 0) {
        unsigned rem = K_TOP; int tb = 0;
        for (int b = 255; b >= 0; --b) {
            if (sblk[b] < rem) rem -= sblk[b];
            else { tb = b; break; }
        }
        sh_tb = tb; sh_rem = rem;
    }
    __syncthreads();
    if (t < 64) sbin[t] = h[sh_tb * 64 + t];
    __syncthreads();
    if (t == 0) {
        unsigned rem = sh_rem; int pfx = sh_tb * 64;
        for (int b = 63; b >= 0; --b) {
            if (sbin[b] < rem) rem -= sbin[b];
            else { pfx = sh_tb * 64 + b; break; }
        }
        tinfo[task * 2]     = (unsigned)pfx;
        tinfo[task * 2 + 1] = rem;
        cnt[task] = 0u;
    }
}

// ---------------- pass 3: compact all keys with bin >= prefix ----------------
__global__ void kCompact(const float* __restrict__ lg, int m, int lvl,
                         const unsigned* __restrict__ tinfo,
                         unsigned* __restrict__ cnt,
                         u64* __restrict__ compbuf) {
    int img = blockIdx.y;
    int task = img * NLVL + lvl;
    unsigned pfx = tinfo[task * 2];
    int j = blockIdx.x * blockDim.x + threadIdx.x;
    if (j < m) {
        unsigned key = key_of(lg[(size_t)img * m + j]);
        if ((key >> L1SHIFT) >= pfx) {
            unsigned pos = atomicAdd(&cnt[task], 1u);
            if (pos < CAP)
                compbuf[(size_t)task * CAP + pos] =
                    ((u64)key << 32) | (unsigned)(~j);
        }
    }
}

// ---------------- pass 4: sort candidates, decode boxes, resort by masked score ----
__global__ __launch_bounds__(1024) void kSortSelect(
        Ptrs p,
        const unsigned* __restrict__ cnt,
        const u64* __restrict__ compbuf,
        float* __restrict__ cscore,
        float4* __restrict__ cbox,
        float4* __restrict__ cobox,
        float* __restrict__ carea,
        unsigned* __restrict__ cog) {
    int task = blockIdx.x;
    int img = task / NLVL, lvl = task % NLVL;
    __shared__ u64 sortbuf[CAP + 1024];   // 40 KB; phase-2 reused as float farr[10240]
    __shared__ u64 buf2[1024];
    u64* buf = sortbuf;
    int n = min((int)cnt[task], CAP);
    for (int i = threadIdx.x; i < CAP; i += 1024)
        buf[i] = (i < n) ? compbuf[(size_t)task * CAP + i] : 0ULL;
    __syncthreads();
    for (int k = 2; k <= CAP; k <<= 1) {
        for (int j2 = k >> 1; j2 > 0; j2 >>= 1) {
            for (int i = threadIdx.x; i < CAP; i += 1024) {
                int pp = i ^ j2;
                if (pp > i) {
                    u64 A = buf[i], B = buf[pp];
                    bool up = ((i & k) == 0);
                    if (up ? (A < B) : (A > B)) { buf[i] = B; buf[pp] = A; }
                }
            }
            __syncthreads();
        }
    }
    const int   MS[5]     = {516096, 129024, 32256, 8064, 2016};
    const int   GW[5]     = {512, 256, 128, 64, 32};
    const float STRIDEF[5]= {4.f, 8.f, 16.f, 32.f, 64.f};
    const int   SIZEI[5]  = {32, 64, 128, 256, 512};
    int r = threadIdx.x;
    float sm = 0.f, x0 = 0.f, y0 = 0.f, x1 = 0.f, y1 = 0.f;
    float b0 = 0.f, b1 = 0.f, b2 = 0.f, b3 = 0.f, area = 0.f;
    if (r < K_TOP) {
        u64 c = buf[r];
        int idx = (int)(~(unsigned)c);
        int m = MS[lvl];
        if ((unsigned)idx >= (unsigned)m) idx = 0;   // safety (never expected)
        const float* lg = p.lg[lvl];
        const float* dl = p.dl[lvl];
        float score = lg[(size_t)img * m + idx];
        int a   = idx % 3;
        int loc = idx / 3;
        int gw  = GW[lvl];
        int x = loc % gw, y = loc / gw;
        double ssz = (double)SIZEI[lvl];
        double arr = (a == 0) ? 0.5 : ((a == 1) ? 1.0 : 2.0);
        double wd = sqrt(ssz * ssz / arr);
        double hd = arr * wd;
        float sx = (float)x * STRIDEF[lvl];
        float sy = (float)y * STRIDEF[lvl];
        float a0 = sx + (float)(-wd * 0.5);
        float a1 = sy + (float)(-hd * 0.5);
        float a2 = sx + (float)( wd * 0.5);
        float a3 = sy + (float)( hd * 0.5);
        float aw = a2 - a0, ah = a3 - a1;
        float acx = a0 + 0.5f * aw, acy = a1 + 0.5f * ah;
        size_t db = ((size_t)img * m + idx) * 4;
        float dx = dl[db], dy = dl[db + 1], dwv = dl[db + 2], dhv = dl[db + 3];
        const float CL = 4.135166556742356f;   // log(1000/16)
        float pw = expf(fminf(dwv, CL)) * aw;
        float ph = expf(fminf(dhv, CL)) * ah;
        float pcx = dx * aw + acx;
        float pcy = dy * ah + acy;
        x0 = pcx - 0.5f * pw; y0 = pcy - 0.5f * ph;
        x1 = pcx + 0.5f * pw; y1 = pcy + 0.5f * ph;
        x0 = fminf(fmaxf(x0, 0.f), 2048.f);
        x1 = fminf(fmaxf(x1, 0.f), 2048.f);
        y0 = fminf(fmaxf(y0, 0.f), 1344.f);
        y1 = fminf(fmaxf(y1, 0.f), 1344.f);
        bool keep = ((x1 - x0) > 0.f) && ((y1 - y0) > 0.f);
        sm = keep ? score : NEGF;
        float off = (float)lvl * 2049.0f;
        b0 = x0 + off; b1 = y0 + off; b2 = x1 + off; b3 = y1 + off;
        area = (b2 - b0) * (b3 - b1);
    }
    __syncthreads();                 // all buf reads done before reuse as farr
    float* farr = (float*)sortbuf;   // [0,1000) score  [1000,2000) area
                                     // [2000,6000) clip box  [6000,10000) offset box
    if (r < K_TOP) {
        farr[r] = sm;
        farr[1000 + r] = area;
        farr[2000 + 4 * r]     = x0;
        farr[2000 + 4 * r + 1] = y0;
        farr[2000 + 4 * r + 2] = x1;
        farr[2000 + 4 * r + 3] = y1;
        farr[6000 + 4 * r]     = b0;
        farr[6000 + 4 * r + 1] = b1;
        farr[6000 + 4 * r + 2] = b2;
        farr[6000 + 4 * r + 3] = b3;
    }
    buf2[r] = (r < K_TOP)
        ? (((u64)key_of(sm) << 32) | (unsigned)(~(unsigned)(lvl * K_TOP + r)))
        : 0ULL;
    __syncthreads();
    for (int k = 2; k <= 1024; k <<= 1) {
        for (int j2 = k >> 1; j2 > 0; j2 >>= 1) {
            int i = r, pp = i ^ j2;
            if (pp > i) {
                u64 A = buf2[i], B = buf2[pp];
                bool up = ((i & k) == 0);
                if (up ? (A < B) : (A > B)) { buf2[i] = B; buf2[pp] = A; }
            }
            __syncthreads();
        }
    }
    if (r < K_TOP) {
        u64 c2 = buf2[r];
        unsigned g2 = ~(unsigned)c2;
        int rsrc = (int)g2 - lvl * K_TOP;    // original within-level rank
        int ci = img * NCAND + lvl * K_TOP + r;
        cscore[ci] = farr[rsrc];
        carea[ci]  = farr[1000 + rsrc];
        cbox[ci]  = make_float4(farr[2000 + 4 * rsrc],     farr[2000 + 4 * rsrc + 1],
                                farr[2000 + 4 * rsrc + 2], farr[2000 + 4 * rsrc + 3]);
        cobox[ci] = make_float4(farr[6000 + 4 * rsrc],     farr[6000 + 4 * rsrc + 1],
                                farr[6000 + 4 * rsrc + 2], farr[6000 + 4 * rsrc + 3]);
        cog[ci] = (unsigned)rsrc;
    }
}

// ---------------- pass 5a: merge 5 sorted lists into global sorted order ----------------
__global__ __launch_bounds__(1024) void kMerge(
        const float* __restrict__ cscore,
        const float4* __restrict__ cbox,
        const float4* __restrict__ cobox,
        const float* __restrict__ carea,
        const unsigned* __restrict__ cog,
        float* __restrict__ ssc,
        float4* __restrict__ sob,
        float* __restrict__ sar,
        float4* __restrict__ sclip) {
    int img = blockIdx.x;
    __shared__ u64 comp[NCAND];
    for (int g = threadIdx.x; g < NCAND; g += 1024) {
        int lv = g / K_TOP;
        unsigned og = (unsigned)(lv * K_TOP) + cog[img * NCAND + g];
        comp[g] = ((u64)key_of(cscore[img * NCAND + g]) << 32) | (unsigned)(~og);
    }
    __syncthreads();
    for (int g = threadIdx.x; g < NCAND; g += 1024) {
        u64 c = comp[g];
        int lv = g / K_TOP;
        int pos = g - lv * K_TOP;    // elements > c within own (desc-sorted) level
        for (int lv2 = 0; lv2 < NLVL; ++lv2) {
            if (lv2 == lv) continue;
            int base = lv2 * K_TOP;
            int lo = 0, hi = K_TOP;
            while (lo < hi) {
                int mid = (lo + hi) >> 1;
                if (comp[base + mid] > c) lo = mid + 1; else hi = mid;
            }
            pos += lo;               // count of elements > c (composites unique)
        }
        int src = img * NCAND + g;
        int dst = img * NCAND + pos;
        ssc[dst]   = cscore[src];
        sob[dst]   = cobox[src];
        sar[dst]   = carea[src];
        sclip[dst] = cbox[src];
    }
}

// ---------------- pass 5b: bit-packed suppression matrix, 16 rows/block ----------------
// Each block: 4 waves x 4 rows. bj loaded once per word per wave, reused for 4 rows.
__global__ __launch_bounds__(256) void kIou(
        const float4* __restrict__ sob,
        const float* __restrict__ sar,
        u64* __restrict__ mat) {
    int img  = blockIdx.y;
    int wid  = threadIdx.x >> 6;
    int lane = threadIdx.x & 63;
    int base = blockIdx.x * 16;
    int row0 = base + wid * 4;
    float4 bi[4]; float ari[4]; bool rv[4];
#pragma unroll
    for (int r = 0; r < 4; ++r) {
        int i = row0 + r;
        rv[r] = (i < NCAND);
        if (rv[r]) { bi[r] = sob[img * NCAND + i]; ari[r] = sar[img * NCAND + i]; }
        else       { bi[r] = make_float4(0.f, 0.f, 0.f, 0.f); ari[r] = 0.f; }
    }
    int wstart = base >> 6;
    for (int w = wstart; w < NWORDS; ++w) {
        int j = w * 64 + lane;
        float4 bj = make_float4(0.f, 0.f, 0.f, 0.f);
        float arj = 0.f;
        bool inb = (j < NCAND);
        if (inb) { bj = sob[img * NCAND + j]; arj = sar[img * NCAND + j]; }
#pragma unroll
        for (int r = 0; r < 4; ++r) {
            bool pred = false;
            if (inb) {
                float ltx = fmaxf(bj.x, bi[r].x), lty = fmaxf(bj.y, bi[r].y);
                float rbx = fminf(bj.z, bi[r].z), rby = fminf(bj.w, bi[r].w);
                float wx = fmaxf(rbx - ltx, 0.f), wy = fmaxf(rby - lty, 0.f);
                float inter = wx * wy;
                float denom = (arj + ari[r]) - inter + 1e-9f;
                float iou = inter / denom;
                pred = iou > 0.7f;
            }
            u64 bits = __ballot(pred);
            if (lane == 0 && rv[r])
                mat[((size_t)(img * NCAND + row0 + r)) * RSTRIDE + w] = bits;
        }
    }
}

// ---------------- pass 5c: scan with wide parallel preload ----------------
// 1024 threads: preload diag/scores in parallel; the serial scan is executed
// redundantly by all threads (all control data is wave-uniform LDS), thread 0
// writes outputs; word-boundary flush covers all future words in one shot.
__global__ __launch_bounds__(1024) void kScan(
        const float* __restrict__ ssc,
        const float4* __restrict__ sclip,
        const u64* __restrict__ mat,
        float* __restrict__ out) {
    int img = blockIdx.x;
    int tid = threadIdx.x;
    __shared__ u64 maskS[NWORDS + 1];
    __shared__ u64 diagS[NWORDS * 64];
    __shared__ float sscS[NCAND];
    __shared__ unsigned pendS[64];
    for (int w = tid; w < NWORDS + 1; w += 1024) maskS[w] = 0ULL;
    // diagS[k] = mat[k][k>>6]  (scattered, but 1024 threads -> ~5 rounds, pipelined)
    for (int k = tid; k < NWORDS * 64; k += 1024)
        diagS[k] = (k < NCAND)
            ? mat[((size_t)(img * NCAND + k)) * RSTRIDE + (k >> 6)] : 0ULL;
    for (int k = tid; k < NCAND; k += 1024)
        sscS[k] = ssc[img * NCAND + k];
    __syncthreads();

    const u64* matI = mat + (size_t)img * NCAND * RSTRIDE;
    int emitted = 0;
    bool done = false;
    for (int w = 0; w < NWORDS && !done; ++w) {
        u64 cur = ~maskS[w];                       // uniform across all threads
        if (w == NWORDS - 1) cur &= (1ULL << (NCAND - (NWORDS - 1) * 64)) - 1ULL;
        int npend = 0;
        while (cur) {
            int b = __builtin_ctzll(cur);
            int i = w * 64 + b;
            float sc = sscS[i];
            if (sc <= -5.0e8f) { done = true; break; }   // all later invalid too
            if (tid == 0) {
                float4 cb = sclip[img * NCAND + i];
                float* o = out + ((size_t)img * NPOST + emitted) * 5;
                o[0] = cb.x; o[1] = cb.y; o[2] = cb.z; o[3] = cb.w; o[4] = sc;
            }
            ++emitted;
            if (emitted == NPOST) { done = true; break; }
            u64 rw = diagS[w * 64 + b];       // same-word suppression (LDS)
            cur &= ~rw;
            cur &= ~(1ULL << b);
            if (tid == 0) pendS[npend] = (unsigned)i;
            ++npend;                          // uniform
        }
        if (!done && npend) {
            __syncthreads();                  // pendS visible to all waves
            int w2 = w + 1 + tid;             // one lane per future word
            if (w2 < NWORDS) {
                u64 acc = 0;
#pragma unroll 4
                for (int k0 = 0; k0 < npend; ++k0)
                    acc |= matI[(size_t)pendS[k0] * RSTRIDE + w2];
                maskS[w2] |= acc;
            }
        }
        __syncthreads();
    }
    for (int rr = emitted + tid; rr < NPOST; rr += 1024) {
        float* o = out + ((size_t)img * NPOST + rr) * 5;
        o[0] = 0.f; o[1] = 0.f; o[2] = 0.f; o[3] = 0.f; o[4] = NEGF;
    }
}

// ---------------- fallback: round-1 sequential NMS (used only if ws too small) ----------------
__global__ __launch_bounds__(1024) void kNMS(
        const float* __restrict__ cscore,
        const float4* __restrict__ cbox,
        const float4* __restrict__ cobox,
        const float* __restrict__ carea,
        float* __restrict__ out) {
    int img = blockIdx.x;
    int tid = threadIdx.x;
    __shared__ u64 warr[16];
    __shared__ float bb[5];
    float s[5], b0[5], b1[5], b2[5], b3[5], ar[5];
#pragma unroll
    for (int k = 0; k < 5; ++k) {
        int j = tid + k * 1024;
        if (j < NCAND) {
            int ci = img * NCAND + j;
            s[k] = cscore[ci];
            float4 b = cobox[ci];
            b0[k] = b.x; b1[k] = b.y; b2[k] = b.z; b3[k] = b.w;
            ar[k] = carea[ci];
        } else {
            s[k] = -3.4e38f;
            b0[k] = b1[k] = b2[k] = b3[k] = 0.f; ar[k] = 0.f;
        }
    }
    for (int step = 0; step < NPOST; ++step) {
        u64 comp = 0ULL;
#pragma unroll
        for (int k = 0; k < 5; ++k) {
            int j = tid + k * 1024;
            unsigned kk = key_of(s[k]);
            u64 c = ((u64)kk << 32) | (unsigned)(~j);
            comp = (c > comp) ? c : comp;
        }
#pragma unroll
        for (int off2 = 32; off2 >= 1; off2 >>= 1) {
            u64 o = __shfl_xor(comp, off2, 64);
            comp = (o > comp) ? o : comp;
        }
        if ((tid & 63) == 0) warr[tid >> 6] = comp;
        __syncthreads();
        u64 best = warr[0];
#pragma unroll
        for (int w = 1; w < 16; ++w) {
            u64 o = warr[w];
            best = (o > best) ? o : best;
        }
        int bidx = (int)(~(unsigned)best);
        float bscore = key_to_float((unsigned)(best >> 32));
        bool valid = bscore > -5.0e8f;
#pragma unroll
        for (int k = 0; k < 5; ++k) {
            int j = tid + k * 1024;
            if (j == bidx) {
                bb[0] = b0[k]; bb[1] = b1[k]; bb[2] = b2[k]; bb[3] = b3[k]; bb[4] = ar[k];
                float* o = out + ((size_t)img * NPOST + step) * 5;
                if (valid) {
                    float4 gb = cbox[img * NCAND + j];
                    o[0] = gb.x; o[1] = gb.y; o[2] = gb.z; o[3] = gb.w; o[4] = bscore;
                } else {
                    o[0] = 0.f; o[1] = 0.f; o[2] = 0.f; o[3] = 0.f; o[4] = NEGF;
                }
            }
        }
        __syncthreads();
        float ib0 = bb[0], ib1 = bb[1], ib2 = bb[2], ib3 = bb[3], iar = bb[4];
#pragma unroll
        for (int k = 0; k < 5; ++k) {
            int j = tid + k * 1024;
            float ltx = fmaxf(b0[k], ib0), lty = fmaxf(b1[k], ib1);
            float rbx = fminf(b2[k], ib2), rby = fminf(b3[k], ib3);
            float wx = fmaxf(rbx - ltx, 0.f), wy = fmaxf(rby - lty, 0.f);
            float inter = wx * wy;
            float denom = ar[k] + iar;
            denom = denom - inter;
            denom = denom + 1e-9f;
            float iou = inter / denom;
            if (iou > 0.7f) s[k] = NEGF;
            if (j == bidx) s[k] = NEGF;
        }
    }
}

extern "C" void kernel_launch(void* const* d_in, const int* in_sizes, int n_in,
                              void* d_out, int out_size, void* d_ws, size_t ws_size,
                              hipStream_t stream) {
    const int MS[5] = {516096, 129024, 32256, 8064, 2016};
    Ptrs P;
    for (int l = 0; l < 5; ++l) {
        P.lg[l] = (const float*)d_in[2 * l];
        P.dl[l] = (const float*)d_in[2 * l + 1];
    }
    char* w = (char*)d_ws;
    size_t off = 0;
    auto alloc = [&](size_t bytes) -> void* {
        void* pp = (void*)(w + off);
        off = (off + bytes + 255) & ~(size_t)255;
        return pp;
    };
    unsigned* hist  = (unsigned*)alloc((size_t)NTASK * NB1 * 4);
    unsigned* tinfo = (unsigned*)alloc(NTASK * 2 * 4);
    unsigned* cnt   = (unsigned*)alloc(NTASK * 4);
    u64* compb      = (u64*)alloc((size_t)NTASK * CAP * 8);
    float*  cscore  = (float*)alloc((size_t)NTASK * K_TOP * 4);
    float4* cbox    = (float4*)alloc((size_t)NTASK * K_TOP * 16);
    float4* cobox   = (float4*)alloc((size_t)NTASK * K_TOP * 16);
    float*  carea   = (float*)alloc((size_t)NTASK * K_TOP * 4);
    unsigned* cog   = (unsigned*)alloc((size_t)NTASK * K_TOP * 4);
    // NMS scratch
    float*  ssc     = (float*)alloc((size_t)NIMG * NCAND * 4);
    float4* sob     = (float4*)alloc((size_t)NIMG * NCAND * 16);
    float*  sar     = (float*)alloc((size_t)NIMG * NCAND * 4);
    float4* sclip   = (float4*)alloc((size_t)NIMG * NCAND * 16);
    u64*    mat     = (u64*)alloc((size_t)NIMG * NCAND * RSTRIDE * 8);
    size_t need = off;
    (void)in_sizes; (void)n_in; (void)out_size;

    size_t nhz = (size_t)NTASK * NB1;
    kZero<<<2048, 256, 0, stream>>>(hist, nhz);
    for (int l = 0; l < 5; ++l) {
        int m4 = MS[l] >> 2;
        int gx = (m4 + 8191) / 8192;       // ~32K elements per block
        dim3 g(gx, NIMG);
        kHist<<<g, 1024, 0, stream>>>(P.lg[l], MS[l], l, hist);
    }
    kSelectBin<<<NTASK, 256, 0, stream>>>(hist, tinfo, cnt);
    for (int l = 0; l < 5; ++l) {
        dim3 g((MS[l] + 255) / 256, NIMG);
        kCompact<<<g, 256, 0, stream>>>(P.lg[l], MS[l], l, tinfo, cnt, compb);
    }
    kSortSelect<<<NTASK, 1024, 0, stream>>>(P, cnt, compb, cscore, cbox, cobox, carea, cog);

    if (ws_size >= need) {
        kMerge<<<NIMG, 1024, 0, stream>>>(cscore, cbox, cobox, carea, cog,
                                          ssc, sob, sar, sclip);
        dim3 gi((NCAND + 15) / 16, NIMG);
        kIou<<<gi, 256, 0, stream>>>(sob, sar, mat);
        kScan<<<NIMG, 1024, 0, stream>>>(ssc, sclip, mat, (float*)d_out);
    } else {
        kNMS<<<NIMG, 1024, 0, stream>>>(cscore, cbox, cobox, carea, (float*)d_out);
    }
}